// Round 5
// baseline (4182.570 us; speedup 1.0000x reference)
//
#include <hip/hip_runtime.h>
#include <stdint.h>

// ---------------------------------------------------------------------------
// RNNClassifier pipeline for MI355X (gfx950). Dtype-agnostic: a sniffer
// kernel detects whether float inputs are f32 or bf16, a converter kernel
// normalizes everything to bf16 in ws, and the epilogue writes d_out in the
// matching dtype. Core pipeline (bf16 MFMA, f32 accum):
//  k_prep : swizzle conv/w_ih/w_hh weights into MFMA B-fragment order
//  k_conv : embedding gather + (conv3|conv5) as one K=640 im2col GEMM -> y
//  k_bn   : finalize BN scale/shift
//  k_gx   : gx = ReLU(BN(y)) @ w_ih^T + b_ih + b_hh, swizzled to C-layout
//  k_lstm : v3 (R5): 16 blocks x 1024 threads (16 waves, 4/SIMD). Wave w
//           owns 4 gate tiles (one per gate group, ntg=gp*16+w) so w_hh is
//           FULLY register-resident (128 VGPR) -> zero in-loop weight
//           traffic. gx software-pipelined one step ahead. v2's L2 stream
//           was latency-bound at 2 waves/SIMD (17k cyc/step, 68% stall).
//  k_attn : attn/attn_out/logits epilogue
//
// MFMA 16x16x32 bf16 layouts (guide m89/m120):
//   A: lane holds A[m=lane&15][k=kt*32+(lane>>4)*8+j], j=0..7
//   B: lane holds B[k=kt*32+(lane>>4)*8+j][n=lane&15]
//   C/D: lane holds D[m=(lane>>4)*4+r][n=lane&15], r=0..3
// ---------------------------------------------------------------------------

typedef __bf16 bf16x8 __attribute__((ext_vector_type(8)));
typedef float  f32x4  __attribute__((ext_vector_type(4)));

__device__ __forceinline__ float bf2f(uint16_t h){
  union { uint32_t u; float f; } v; v.u = ((uint32_t)h) << 16; return v.f;
}
__device__ __forceinline__ uint16_t f2bf(float f){
  union { float f; uint32_t u; } v; v.f = f;
  return (uint16_t)((v.u + 0x7FFFu + ((v.u >> 16) & 1u)) >> 16);
}
__device__ __forceinline__ bf16x8 ld_frag(const uint16_t* p){
  union { int4 i; bf16x8 b; } u; u.i = *(const int4*)p; return u.b;
}
__device__ __forceinline__ f32x4 mfma16(bf16x8 a, bf16x8 b, f32x4 c){
  return __builtin_amdgcn_mfma_f32_16x16x32_bf16(a, b, c, 0, 0, 0);
}
__device__ __forceinline__ float sigm(float x){
  return __builtin_amdgcn_rcpf(1.f + __expf(-x));
}
__device__ __forceinline__ float tanh_(float x){
  return 2.f * __builtin_amdgcn_rcpf(1.f + __expf(-2.f * x)) - 1.f;
}

// ---------------------------------------------------------------------------
__global__ __launch_bounds__(256) void k_sniff(const uint32_t* __restrict__ e,
                                               int* __restrict__ flag)
{
  __shared__ int cnt;
  int tid = threadIdx.x;
  if (tid == 0) cnt = 0;
  __syncthreads();
  uint32_t u = e[tid];
  uint32_t ex = (u >> 7) & 0xFFu;
  if (ex >= 0x60u && ex <= 0x7Eu) atomicAdd(&cnt, 1);
  __syncthreads();
  if (tid == 0) flag[0] = (cnt >= 192) ? 1 : 0;
}

// ---------------------------------------------------------------------------
struct CvtDesc { const void* s; uint16_t* d; int n; int c0; };
struct CvtArgs { CvtDesc a[13]; };

__global__ __launch_bounds__(256) void k_cvt(CvtArgs A, const int* __restrict__ flag)
{
  int ch = blockIdx.x;
  int i = 0;
  #pragma unroll
  for (int k = 1; k < 13; ++k) if (ch >= A.a[k].c0) i = k;
  const void* s = A.a[i].s;
  uint16_t*   d = A.a[i].d;
  int n = A.a[i].n;
  int base = (ch - A.a[i].c0) * 4096 + threadIdx.x;
  int isb = *flag;
  #pragma unroll 4
  for (int r = 0; r < 16; ++r) {
    int idx = base + r * 256;
    if (idx < n)
      d[idx] = isb ? ((const uint16_t*)s)[idx] : f2bf(((const float*)s)[idx]);
  }
}

// ---------------------------------------------------------------------------
__global__ __launch_bounds__(256) void k_prep(
    const uint16_t* __restrict__ c1w, const uint16_t* __restrict__ c2w,
    const uint16_t* __restrict__ wih, const uint16_t* __restrict__ whh,
    uint16_t* __restrict__ fragC, uint16_t* __restrict__ fragI,
    uint16_t* __restrict__ fragH, float* __restrict__ bnbuf,
    uint16_t* __restrict__ wsH, float* __restrict__ wsC)
{
  int g = blockIdx.x * 256 + threadIdx.x;
  if (g < 20480) {                       // conv B fragments (320 tiles)
    int tile = g >> 6, lane = g & 63;
    int kt = tile >> 4, nt = tile & 15;
    int q = lane >> 4, c16 = lane & 15;
    int dlt = kt >> 2;
    int o = nt * 16 + c16;
    union { int4 i; uint16_t u[8]; } v;
    #pragma unroll
    for (int j = 0; j < 8; ++j) {
      int i = (kt & 3) * 32 + q * 8 + j;
      uint16_t val = 0;
      if (o < 128) { int k = dlt - 1; if (k >= 0 && k < 3) val = c1w[(o*128 + i)*3 + k]; }
      else         { int k = dlt;     if (k < 5)           val = c2w[((o-128)*128 + i)*5 + k]; }
      v.u[j] = val;
    }
    *(int4*)(fragC + tile * 512 + lane * 8) = v.i;
  } else if (g < 53248) {                // w_ih fragments (512 tiles)
    int gg = g - 20480;
    int tile = gg >> 6, lane = gg & 63;
    int nt = tile >> 3, kt = tile & 7;
    int q = lane >> 4, c16 = lane & 15;
    *(int4*)(fragI + tile * 512 + lane * 8) =
        *(const int4*)(wih + (nt*16 + c16)*256 + kt*32 + q*8);
  } else if (g < 86016) {                // w_hh fragments (512 tiles)
    int gg = g - 53248;
    int tile = gg >> 6, lane = gg & 63;
    int nt = tile >> 3, kt = tile & 7;
    int q = lane >> 4, c16 = lane & 15;
    *(int4*)(fragH + tile * 512 + lane * 8) =
        *(const int4*)(whh + (nt*16 + c16)*256 + kt*32 + q*8);
  } else if (g < 94208) {                // zero wsH
    ((int4*)wsH)[g - 86016] = make_int4(0,0,0,0);
  } else if (g < 110592) {               // zero wsC
    ((int4*)wsC)[g - 94208] = make_int4(0,0,0,0);
  } else if (g < 110720) {               // zero bn sums
    ((int4*)bnbuf)[g - 110592] = make_int4(0,0,0,0);
  }
}

// ---------------------------------------------------------------------------
__global__ __launch_bounds__(256) void k_conv(
    const int* __restrict__ x, const uint16_t* __restrict__ etab,
    const uint16_t* __restrict__ fragC,
    const uint16_t* __restrict__ c1b, const uint16_t* __restrict__ c2b,
    uint16_t* __restrict__ y, float* __restrict__ bnbuf)
{
  __shared__ __align__(16) uint16_t embS[68 * 136];
  int blk = blockIdx.x;
  int b = blk >> 3, t0 = (blk & 7) * 64;
  int tid = threadIdx.x;
  int lane = tid & 63, w = tid >> 6;
  int q = lane >> 4, c16 = lane & 15;

  for (int s = tid; s < 1088; s += 256) {      // 68 rows x 16 segs of 16B
    int r = s >> 4, seg = s & 15;
    int t = t0 - 2 + r;
    int4 val = make_int4(0,0,0,0);
    if (t >= 0 && t < 512) {
      int idx = x[b*512 + t];
      val = *(const int4*)(etab + (size_t)idx*128 + seg*8);
    }
    *(int4*)(embS + r*136 + seg*8) = val;
  }
  __syncthreads();

  f32x4 acc[4][4];
  #pragma unroll
  for (int i = 0; i < 4; ++i)
    #pragma unroll
    for (int j = 0; j < 4; ++j) acc[i][j] = (f32x4){0.f,0.f,0.f,0.f};

  #pragma unroll 4
  for (int kt = 0; kt < 20; ++kt) {
    int dlt = kt >> 2;
    int i0 = (kt & 3)*32 + q*8;
    bf16x8 a[4];
    #pragma unroll
    for (int Mt = 0; Mt < 4; ++Mt)
      a[Mt] = ld_frag(embS + (Mt*16 + c16 + dlt)*136 + i0);
    #pragma unroll
    for (int ntl = 0; ntl < 4; ++ntl) {
      int nt = w*4 + ntl;
      bf16x8 bf = ld_frag(fragC + (kt*16 + nt)*512 + lane*8);
      #pragma unroll
      for (int Mt = 0; Mt < 4; ++Mt)
        acc[ntl][Mt] = mfma16(a[Mt], bf, acc[ntl][Mt]);
    }
  }

  #pragma unroll
  for (int ntl = 0; ntl < 4; ++ntl) {
    int ch = (w*4 + ntl)*16 + c16;
    float bias = bf2f(ch < 128 ? c1b[ch] : c2b[ch - 128]);
    float s0 = 0.f, s1 = 0.f;
    #pragma unroll
    for (int Mt = 0; Mt < 4; ++Mt) {
      #pragma unroll
      for (int r = 0; r < 4; ++r) {
        float v = acc[ntl][Mt][r] + bias;
        int t = t0 + Mt*16 + q*4 + r;
        y[((size_t)b*512 + t)*256 + ch] = f2bf(v);
        s0 += v; s1 += v*v;
      }
    }
    s0 += __shfl_xor(s0, 16); s0 += __shfl_xor(s0, 32);
    s1 += __shfl_xor(s1, 16); s1 += __shfl_xor(s1, 32);
    if (q == 0) { atomicAdd(&bnbuf[ch], s0); atomicAdd(&bnbuf[256 + ch], s1); }
  }
}

// ---------------------------------------------------------------------------
__global__ void k_bn(const uint16_t* __restrict__ gamma,
                     const uint16_t* __restrict__ beta,
                     float* __restrict__ bnbuf)
{
  int c = threadIdx.x;
  const float inv = 1.f / 131072.f;
  float mean = bnbuf[c] * inv;
  float var  = fmaxf(bnbuf[256 + c] * inv - mean*mean, 0.f);
  float sc   = bf2f(gamma[c]) * rsqrtf(var + 1e-5f);
  bnbuf[512 + c] = sc;
  bnbuf[768 + c] = bf2f(beta[c]) - mean * sc;
}

// ---------------------------------------------------------------------------
__global__ __launch_bounds__(256) void k_gx(
    const uint16_t* __restrict__ y, const float* __restrict__ bnbuf,
    const uint16_t* __restrict__ fragI, const uint16_t* __restrict__ bih,
    const uint16_t* __restrict__ bhh, uint16_t* __restrict__ gx, int tbase)
{
  __shared__ __align__(16) uint16_t aS[16384];
  int Mblk = blockIdx.x, Nblk = blockIdx.y;
  int tl = Mblk >> 2;
  int b0 = (Mblk & 3) * 64;
  int t = tbase + tl;
  int tid = threadIdx.x, lane = tid & 63, w = tid >> 6;
  int q = lane >> 4, c16 = lane & 15;

  for (int s = tid; s < 2048; s += 256) {
    int row = s >> 5, seg = s & 31;
    union { int4 i; uint16_t u[8]; } vv, oo;
    vv.i = *(const int4*)(y + ((size_t)(b0 + row)*512 + t)*256 + seg*8);
    #pragma unroll
    for (int j = 0; j < 8; ++j) {
      int ch = seg*8 + j;
      float f = bf2f(vv.u[j]) * bnbuf[512 + ch] + bnbuf[768 + ch];
      oo.u[j] = f2bf(fmaxf(f, 0.f));
    }
    int Mt = row >> 4, mL = row & 15, kt2 = seg >> 2, qq = seg & 3;
    *(int4*)(aS + ((Mt*8 + kt2)*64 + qq*16 + mL)*8) = oo.i;
  }
  __syncthreads();

  f32x4 acc[4][4];
  #pragma unroll
  for (int ntl = 0; ntl < 4; ++ntl) {
    int n = (Nblk*16 + w*4 + ntl)*16 + c16;
    float bias = bf2f(bih[n]) + bf2f(bhh[n]);
    #pragma unroll
    for (int Mt = 0; Mt < 4; ++Mt) acc[ntl][Mt] = (f32x4){bias,bias,bias,bias};
  }
  #pragma unroll
  for (int kt = 0; kt < 8; ++kt) {
    bf16x8 a[4];
    #pragma unroll
    for (int Mt = 0; Mt < 4; ++Mt)
      a[Mt] = ld_frag(aS + ((Mt*8 + kt)*64 + lane)*8);
    #pragma unroll
    for (int ntl = 0; ntl < 4; ++ntl) {
      int nt = Nblk*16 + w*4 + ntl;
      bf16x8 bf = ld_frag(fragI + ((size_t)(nt*8 + kt))*512 + lane*8);
      #pragma unroll
      for (int Mt = 0; Mt < 4; ++Mt)
        acc[ntl][Mt] = mfma16(a[Mt], bf, acc[ntl][Mt]);
    }
  }
  #pragma unroll
  for (int ntl = 0; ntl < 4; ++ntl) {
    int nt = Nblk*16 + w*4 + ntl;
    #pragma unroll
    for (int Mt = 0; Mt < 4; ++Mt) {
      int bg = (Mblk & 3)*4 + Mt;
      uint32_t lo = (uint32_t)f2bf(acc[ntl][Mt][0]) | ((uint32_t)f2bf(acc[ntl][Mt][1]) << 16);
      uint32_t hi = (uint32_t)f2bf(acc[ntl][Mt][2]) | ((uint32_t)f2bf(acc[ntl][Mt][3]) << 16);
      uint2 vv = {lo, hi};
      *(uint2*)(gx + ((size_t)(tl*16 + bg))*16384 + nt*256 + lane*4) = vv;
    }
  }
}

// ---------------------------------------------------------------------------
// k_lstm v3: 16 blocks x 1024 threads (16 waves, 4/SIMD). Block bg owns
// batch rows [16bg,16bg+16). Wave w owns units [16w,16w+16): one gate tile
// per gate group, ntg[gp] = gp*16 + w, so i/f/g/o for unit u=16w+c16 land in
// the same lane. w_hh fully register-resident: breg[4][8] = 128 VGPR.
// Per step: prefetch gx(t+1) -> acc init from gx(t) -> 8x(ds_read_b128 +
// 4 MFMA) -> 4 LSTM cells/lane -> h to LDS dbuf -> barrier.
// ---------------------------------------------------------------------------
__global__ __launch_bounds__(1024, 4) void k_lstm(
    const uint16_t* __restrict__ gx, const uint16_t* __restrict__ fragH,
    const int* __restrict__ lengths, uint16_t* __restrict__ wsH,
    float* __restrict__ wsC, float* __restrict__ hn,
    int tbase, int tcount, int last)
{
  __shared__ __align__(16) uint16_t aS[2 * 4096];
  int bg = blockIdx.x;
  int tid = threadIdx.x, lane = tid & 63, w = tid >> 6;   // w = 0..15
  int q = lane >> 4, c16 = lane & 15;

  if (tid < 512)
    ((int4*)aS)[tid] = ((const int4*)(wsH + bg*4096))[tid];  // h carry -> buf0

  int li[4];
  #pragma unroll
  for (int r = 0; r < 4; ++r) li[r] = lengths[bg*16 + q*4 + r];
  int Tmax = lengths[bg*16];                   // lengths sorted descending

  float cr[4], hr[4];
  #pragma unroll
  for (int r = 0; r < 4; ++r)
    cr[r] = wsC[(bg*16 + q*4 + r)*256 + w*16 + c16];

  int ntg[4];
  bf16x8 breg[4][8];                           // w_hh fully resident
  #pragma unroll
  for (int gp = 0; gp < 4; ++gp) {
    ntg[gp] = gp*16 + w;
    #pragma unroll
    for (int kt = 0; kt < 8; ++kt)
      breg[gp][kt] = ld_frag(fragH + (ntg[gp]*8 + kt)*512 + lane*8);
  }

  // h LDS address for unit u = 16w + c16, row m = q*4 + r (A-frag layout):
  // idx = (u>>5)*512 + ((u>>3)&3)*128 + m*8 + (u&7)
  int u = w*16 + c16;
  int hb = (u >> 5)*512 + ((u >> 3) & 3)*128 + q*32 + (u & 7);
  __syncthreads();

  #pragma unroll
  for (int r = 0; r < 4; ++r) hr[r] = bf2f(aS[hb + r*8]);

  int cur = 0;
  int tEnd = min(tbase + tcount, Tmax);

  uint2 gcur[4], gnxt[4];
  if (tEnd > tbase) {
    const uint16_t* g0 = gx + (size_t)bg*16384 + lane*4;
    #pragma unroll
    for (int gp = 0; gp < 4; ++gp)
      gcur[gp] = *(const uint2*)(g0 + ntg[gp]*256);
  }

  for (int t = tbase; t < tEnd; ++t) {
    const uint16_t* Ar = aS + cur*4096;
    uint16_t* Aw = aS + (cur ^ 1)*4096;

    // prefetch next step's gx (consumed next iteration)
    {
      int tn = (t + 1 < tEnd) ? (t + 1 - tbase) : (t - tbase);
      const uint16_t* gN = gx + ((size_t)(tn*16 + bg))*16384 + lane*4;
      #pragma unroll
      for (int gp = 0; gp < 4; ++gp)
        gnxt[gp] = *(const uint2*)(gN + ntg[gp]*256);
    }

    // acc init from gx(t)
    f32x4 acc[4];
    #pragma unroll
    for (int gp = 0; gp < 4; ++gp) {
      acc[gp][0] = bf2f((uint16_t)(gcur[gp].x & 0xffffu));
      acc[gp][1] = bf2f((uint16_t)(gcur[gp].x >> 16));
      acc[gp][2] = bf2f((uint16_t)(gcur[gp].y & 0xffffu));
      acc[gp][3] = bf2f((uint16_t)(gcur[gp].y >> 16));
    }

    // GEMM: all weights in registers, A from LDS
    #pragma unroll
    for (int kt = 0; kt < 8; ++kt) {
      bf16x8 a = ld_frag(Ar + kt*512 + lane*8);
      #pragma unroll
      for (int gp = 0; gp < 4; ++gp)
        acc[gp] = mfma16(a, breg[gp][kt], acc[gp]);
    }

    // gates: 4 cells per lane
    #pragma unroll
    for (int r = 0; r < 4; ++r) {
      bool upd = (t < li[r]);
      float gi = acc[0][r];
      float gf = acc[1][r];
      float gg = acc[2][r];
      float go = acc[3][r];
      float cn = sigm(gf)*cr[r] + sigm(gi)*tanh_(gg);
      float hw = sigm(go)*tanh_(cn);
      cn = upd ? cn : cr[r];
      hw = upd ? hw : hr[r];
      cr[r] = cn; hr[r] = hw;
      Aw[hb + r*8] = f2bf(hw);
    }

    #pragma unroll
    for (int gp = 0; gp < 4; ++gp) gcur[gp] = gnxt[gp];
    __syncthreads();
    cur ^= 1;
  }

  if (tid < 512)
    ((int4*)(wsH + bg*4096))[tid] = ((const int4*)(aS + cur*4096))[tid];
  #pragma unroll
  for (int r = 0; r < 4; ++r)
    wsC[(bg*16 + q*4 + r)*256 + w*16 + c16] = cr[r];

  if (last) {
    for (int i = tid; i < 4096; i += 1024) {
      int m = i >> 8, uu = i & 255;
      hn[(bg*16 + m)*256 + uu] =
          bf2f(aS[cur*4096 + (uu>>5)*512 + ((uu>>3)&3)*128 + m*8 + (uu&7)]);
    }
  }
}

// ---------------------------------------------------------------------------
__global__ __launch_bounds__(256) void k_attn(
    const uint16_t* __restrict__ y, const float* __restrict__ hn,
    const uint16_t* __restrict__ linw, const uint16_t* __restrict__ linb,
    void* __restrict__ outv, const int* __restrict__ flag)
{
  __shared__ float hnS[256];
  __shared__ float attnS[512];
  int b = blockIdx.x;
  int tid = threadIdx.x, lane = tid & 63, w = tid >> 6;
  int isb = *flag;
  hnS[tid] = hn[b*256 + tid];
  __syncthreads();
  for (int t = w; t < 512; t += 4) {
    uint2 d = *(const uint2*)(y + ((size_t)b*512 + t)*256 + lane*4);
    float s = bf2f((uint16_t)(d.x & 0xffffu)) * hnS[lane*4 + 0]
            + bf2f((uint16_t)(d.x >> 16))     * hnS[lane*4 + 1]
            + bf2f((uint16_t)(d.y & 0xffffu)) * hnS[lane*4 + 2]
            + bf2f((uint16_t)(d.y >> 16))     * hnS[lane*4 + 3];
    #pragma unroll
    for (int off = 32; off >= 1; off >>= 1) s += __shfl_xor(s, off);
    if (lane == 0) attnS[t] = s * 0.0625f;     // 1/sqrt(256)
  }
  __syncthreads();
  float acc = 0.f;
  #pragma unroll 4
  for (int t = 0; t < 512; ++t)
    acc += attnS[t] * bf2f(y[((size_t)b*512 + t)*256 + tid]);
  if (isb) ((uint16_t*)outv)[7936 + b*256 + tid] = f2bf(acc);
  else     ((float*)outv)[7936 + b*256 + tid] = acc;
  if (tid < 31) {
    float a2 = bf2f(linb[tid]);
    for (int k = 0; k < 256; ++k) a2 += hnS[k] * bf2f(linw[tid*256 + k]);
    if (isb) ((uint16_t*)outv)[b*31 + tid] = f2bf(a2);
    else     ((float*)outv)[b*31 + tid] = a2;
  }
}

// ---------------------------------------------------------------------------
extern "C" void kernel_launch(void* const* d_in, const int* in_sizes, int n_in,
                              void* d_out, int out_size, void* d_ws, size_t ws_size,
                              hipStream_t stream)
{
  (void)in_sizes; (void)out_size;
  if (n_in < 15) return;
  const int* x   = (const int*)d_in[0];
  const int* len = (const int*)d_in[1];

  uint8_t* p = (uint8_t*)d_ws;
  auto take = [&](size_t n){ uint8_t* r = p; p += (n + 255) & ~(size_t)255; return r; };
  int*      flag  = (int*)take(256);
  uint16_t* c1bC  = (uint16_t*)take(256);
  uint16_t* c2bC  = (uint16_t*)take(256);
  uint16_t* bngC  = (uint16_t*)take(512);
  uint16_t* bnbC  = (uint16_t*)take(512);
  uint16_t* bihC  = (uint16_t*)take(2048);
  uint16_t* bhhC  = (uint16_t*)take(2048);
  uint16_t* linwC = (uint16_t*)take(15872);
  uint16_t* linbC = (uint16_t*)take(64);
  uint16_t* fragC = (uint16_t*)take(327680);
  uint16_t* fragI = (uint16_t*)take(524288);
  uint16_t* fragH = (uint16_t*)take(524288);
  float*    bnbuf = (float*)take(4096);
  uint16_t* wsH   = (uint16_t*)take(131072);
  float*    wsC   = (float*)take(262144);
  float*    hnbuf = (float*)take(262144);
  uint16_t* y     = (uint16_t*)take(67108864ull);
  uint16_t* gxb   = (uint16_t*)take(67108864ull);
  if ((size_t)(p - (uint8_t*)d_ws) > ws_size) return;

  // big converted tensors live inside gxb (dead before k_gx first writes it)
  uint16_t* etabC = gxb;
  uint16_t* c1wC  = (uint16_t*)((uint8_t*)gxb + 16u*1024*1024);
  uint16_t* c2wC  = (uint16_t*)((uint8_t*)gxb + 17u*1024*1024);
  uint16_t* wihC  = (uint16_t*)((uint8_t*)gxb + 18u*1024*1024);
  uint16_t* whhC  = (uint16_t*)((uint8_t*)gxb + 19u*1024*1024);

  k_sniff<<<1, 256, 0, stream>>>((const uint32_t*)d_in[2], flag);

  CvtArgs A;
  int c0 = 0;
  auto put = [&](int i, const void* s, uint16_t* d, int n){
    A.a[i].s = s; A.a[i].d = d; A.a[i].n = n; A.a[i].c0 = c0;
    c0 += (n + 4095) / 4096;
  };
  put(0,  d_in[2],  etabC, 6400000);
  put(1,  d_in[3],  c1wC,  49152);
  put(2,  d_in[4],  c1bC,  128);
  put(3,  d_in[5],  c2wC,  81920);
  put(4,  d_in[6],  c2bC,  128);
  put(5,  d_in[7],  bngC,  256);
  put(6,  d_in[8],  bnbC,  256);
  put(7,  d_in[9],  wihC,  262144);
  put(8,  d_in[10], whhC,  262144);
  put(9,  d_in[11], bihC,  1024);
  put(10, d_in[12], bhhC,  1024);
  put(11, d_in[13], linwC, 7936);
  put(12, d_in[14], linbC, 31);
  k_cvt<<<c0, 256, 0, stream>>>(A, flag);

  k_prep<<<512, 256, 0, stream>>>(c1wC, c2wC, wihC, whhC, fragC, fragI, fragH,
                                  bnbuf, wsH, wsC);
  k_conv<<<2048, 256, 0, stream>>>(x, etabC, fragC, c1bC, c2bC, y, bnbuf);
  k_bn<<<1, 256, 0, stream>>>(bngC, bnbC, bnbuf);
  for (int c = 0; c < 4; ++c) {
    k_gx<<<dim3(512, 4), 256, 0, stream>>>(y, bnbuf, fragI, bihC, bhhC, gxb, c*128);
    k_lstm<<<16, 1024, 0, stream>>>(gxb, fragH, len, wsH, wsC, hnbuf,
                                    c*128, 128, (c == 3) ? 1 : 0);
  }
  k_attn<<<256, 256, 0, stream>>>(y, hnbuf, linwC, linbC, d_out, flag);
}

// Round 6
// 2921.101 us; speedup vs baseline: 1.4318x; 1.4318x over previous
//
#include <hip/hip_runtime.h>
#include <stdint.h>

// ---------------------------------------------------------------------------
// RNNClassifier pipeline for MI355X (gfx950). Dtype-agnostic input handling
// (sniffer + converter to bf16). Core pipeline (MFMA, f32 accum):
//  k_prep : conv/w_ih weights -> bf16 MFMA B-frags; w_hh -> fp8 e4m3 B-frags
//           scaled x16 (k_lstm v4); zero carries.
//  k_conv : embedding gather + (conv3|conv5) as one K=640 im2col GEMM -> y
//  k_bn   : finalize BN scale/shift
//  k_gx   : gx = ReLU(BN(y)) @ w_ih^T + b_ih + b_hh, swizzled to C-layout
//  k_lstm : v4: 16 blocks x 512 thr (8 waves, 2/SIMD, 256-VGPR cap).
//           w_hh FULLY register-resident as fp8 (128 VGPR). h quantized as
//           split fp8 (hi + residual) -> two MFMA chains, recombined
//           g = gx + acc1/256 + acc2/4096 (h-quant error cancels to ~bf16).
//           gx staged to LDS via global_load_lds dbuf. R5 lesson: bf16
//           residency is infeasible (w_hh = entire CU VGPR file); R5's
//           VGPR_Count=64 proved the allocator spilled breg.
//  k_attn : attn/attn_out/logits epilogue
//
// MFMA 16x16x32 layouts (bf16 verified m89/m120; fp8 same index pattern,
// bytes instead of words):
//   A: lane holds A[m=lane&15][k=(lane>>4)*8+j], j=0..7
//   B: lane holds B[k=(lane>>4)*8+j][n=lane&15]
//   C/D: lane holds D[m=(lane>>4)*4+r][n=lane&15], r=0..3
// ---------------------------------------------------------------------------

typedef __bf16 bf16x8 __attribute__((ext_vector_type(8)));
typedef float  f32x4  __attribute__((ext_vector_type(4)));

__device__ __forceinline__ float bf2f(uint16_t h){
  union { uint32_t u; float f; } v; v.u = ((uint32_t)h) << 16; return v.f;
}
__device__ __forceinline__ uint16_t f2bf(float f){
  union { float f; uint32_t u; } v; v.f = f;
  return (uint16_t)((v.u + 0x7FFFu + ((v.u >> 16) & 1u)) >> 16);
}
__device__ __forceinline__ bf16x8 ld_frag(const uint16_t* p){
  union { int4 i; bf16x8 b; } u; u.i = *(const int4*)p; return u.b;
}
__device__ __forceinline__ f32x4 mfma16(bf16x8 a, bf16x8 b, f32x4 c){
  return __builtin_amdgcn_mfma_f32_16x16x32_bf16(a, b, c, 0, 0, 0);
}
__device__ __forceinline__ float sigm(float x){
  return __builtin_amdgcn_rcpf(1.f + __expf(-x));
}
__device__ __forceinline__ float tanh_(float x){
  return 2.f * __builtin_amdgcn_rcpf(1.f + __expf(-2.f * x)) - 1.f;
}

typedef long i64_t;
__device__ __forceinline__ i64_t mk64(uint32_t lo, uint32_t hi){
  union { uint2 u; i64_t l; } t; t.u = make_uint2(lo, hi); return t.l;
}
__device__ __forceinline__ f32x4 mfma8(i64_t a, i64_t b, f32x4 c){
  return __builtin_amdgcn_mfma_f32_16x16x32_fp8_fp8(a, b, c, 0, 0, 0);
}
__device__ __forceinline__ void dma16(const void* g, void* l){
  __builtin_amdgcn_global_load_lds(
      (const __attribute__((address_space(1))) uint32_t*)g,
      (__attribute__((address_space(3))) uint32_t*)l, 16, 0, 0);
}
// write h as [H|L] byte pair into A-frag LDS layout
__device__ __forceinline__ void emit_h(uint8_t* buf, int cellbase, int m,
                                       int j, float h){
  float h16 = h * 16.f;
  int p1 = __builtin_amdgcn_cvt_pk_fp8_f32(h16, h16, 0, false);
  float dec = __builtin_amdgcn_cvt_f32_fp8(p1, 0);
  float r16 = (h16 - dec) * 16.f;
  int p2 = __builtin_amdgcn_cvt_pk_fp8_f32(r16, r16, 0, false);
  *(uint16_t*)(buf + (cellbase + m)*16 + 2*j) =
      (uint16_t)((p1 & 0xff) | ((p2 & 0xff) << 8));
}

// ---------------------------------------------------------------------------
__global__ __launch_bounds__(256) void k_sniff(const uint32_t* __restrict__ e,
                                               int* __restrict__ flag)
{
  __shared__ int cnt;
  int tid = threadIdx.x;
  if (tid == 0) cnt = 0;
  __syncthreads();
  uint32_t u = e[tid];
  uint32_t ex = (u >> 7) & 0xFFu;
  if (ex >= 0x60u && ex <= 0x7Eu) atomicAdd(&cnt, 1);
  __syncthreads();
  if (tid == 0) flag[0] = (cnt >= 192) ? 1 : 0;
}

// ---------------------------------------------------------------------------
struct CvtDesc { const void* s; uint16_t* d; int n; int c0; };
struct CvtArgs { CvtDesc a[13]; };

__global__ __launch_bounds__(256) void k_cvt(CvtArgs A, const int* __restrict__ flag)
{
  int ch = blockIdx.x;
  int i = 0;
  #pragma unroll
  for (int k = 1; k < 13; ++k) if (ch >= A.a[k].c0) i = k;
  const void* s = A.a[i].s;
  uint16_t*   d = A.a[i].d;
  int n = A.a[i].n;
  int base = (ch - A.a[i].c0) * 4096 + threadIdx.x;
  int isb = *flag;
  #pragma unroll 4
  for (int r = 0; r < 16; ++r) {
    int idx = base + r * 256;
    if (idx < n)
      d[idx] = isb ? ((const uint16_t*)s)[idx] : f2bf(((const float*)s)[idx]);
  }
}

// ---------------------------------------------------------------------------
__global__ __launch_bounds__(256) void k_prep(
    const uint16_t* __restrict__ c1w, const uint16_t* __restrict__ c2w,
    const uint16_t* __restrict__ wih, const uint16_t* __restrict__ whh,
    uint16_t* __restrict__ fragC, uint16_t* __restrict__ fragI,
    uint2* __restrict__ fragH8, float* __restrict__ bnbuf,
    float* __restrict__ wsHf, float* __restrict__ wsC)
{
  int g = blockIdx.x * 256 + threadIdx.x;
  if (g < 20480) {                       // conv B fragments (320 tiles)
    int tile = g >> 6, lane = g & 63;
    int kt = tile >> 4, nt = tile & 15;
    int q = lane >> 4, c16 = lane & 15;
    int dlt = kt >> 2;
    int o = nt * 16 + c16;
    union { int4 i; uint16_t u[8]; } v;
    #pragma unroll
    for (int j = 0; j < 8; ++j) {
      int i = (kt & 3) * 32 + q * 8 + j;
      uint16_t val = 0;
      if (o < 128) { int k = dlt - 1; if (k >= 0 && k < 3) val = c1w[(o*128 + i)*3 + k]; }
      else         { int k = dlt;     if (k < 5)           val = c2w[((o-128)*128 + i)*5 + k]; }
      v.u[j] = val;
    }
    *(int4*)(fragC + tile * 512 + lane * 8) = v.i;
  } else if (g < 53248) {                // w_ih bf16 fragments (512 tiles)
    int gg = g - 20480;
    int tile = gg >> 6, lane = gg & 63;
    int nt = tile >> 3, kt = tile & 7;
    int q = lane >> 4, c16 = lane & 15;
    *(int4*)(fragI + tile * 512 + lane * 8) =
        *(const int4*)(wih + (nt*16 + c16)*256 + kt*32 + q*8);
  } else if (g < 86016) {                // w_hh fp8 fragments (x16 scale)
    int gg = g - 53248;
    int tile = gg >> 6, lane = gg & 63;
    int nt = tile >> 3, kt = tile & 7;
    int q = lane >> 4, c16 = lane & 15;
    const uint16_t* src = whh + (nt*16 + c16)*256 + kt*32 + q*8;
    float f[8];
    #pragma unroll
    for (int j = 0; j < 8; ++j) f[j] = bf2f(src[j]) * 16.f;
    int lo = __builtin_amdgcn_cvt_pk_fp8_f32(f[0], f[1], 0, false);
    lo     = __builtin_amdgcn_cvt_pk_fp8_f32(f[2], f[3], lo, true);
    int hi = __builtin_amdgcn_cvt_pk_fp8_f32(f[4], f[5], 0, false);
    hi     = __builtin_amdgcn_cvt_pk_fp8_f32(f[6], f[7], hi, true);
    fragH8[tile*64 + lane] = make_uint2((uint32_t)lo, (uint32_t)hi);
  } else if (g < 102400) {               // zero wsHf (65536 f32)
    ((int4*)wsHf)[g - 86016] = make_int4(0,0,0,0);
  } else if (g < 118784) {               // zero wsC (65536 f32)
    ((int4*)wsC)[g - 102400] = make_int4(0,0,0,0);
  } else if (g < 118912) {               // zero bn sums (512 f32)
    ((int4*)bnbuf)[g - 118784] = make_int4(0,0,0,0);
  }
}

// ---------------------------------------------------------------------------
__global__ __launch_bounds__(256) void k_conv(
    const int* __restrict__ x, const uint16_t* __restrict__ etab,
    const uint16_t* __restrict__ fragC,
    const uint16_t* __restrict__ c1b, const uint16_t* __restrict__ c2b,
    uint16_t* __restrict__ y, float* __restrict__ bnbuf)
{
  __shared__ __align__(16) uint16_t embS[68 * 136];
  int blk = blockIdx.x;
  int b = blk >> 3, t0 = (blk & 7) * 64;
  int tid = threadIdx.x;
  int lane = tid & 63, w = tid >> 6;
  int q = lane >> 4, c16 = lane & 15;

  for (int s = tid; s < 1088; s += 256) {      // 68 rows x 16 segs of 16B
    int r = s >> 4, seg = s & 15;
    int t = t0 - 2 + r;
    int4 val = make_int4(0,0,0,0);
    if (t >= 0 && t < 512) {
      int idx = x[b*512 + t];
      val = *(const int4*)(etab + (size_t)idx*128 + seg*8);
    }
    *(int4*)(embS + r*136 + seg*8) = val;
  }
  __syncthreads();

  f32x4 acc[4][4];
  #pragma unroll
  for (int i = 0; i < 4; ++i)
    #pragma unroll
    for (int j = 0; j < 4; ++j) acc[i][j] = (f32x4){0.f,0.f,0.f,0.f};

  #pragma unroll 4
  for (int kt = 0; kt < 20; ++kt) {
    int dlt = kt >> 2;
    int i0 = (kt & 3)*32 + q*8;
    bf16x8 a[4];
    #pragma unroll
    for (int Mt = 0; Mt < 4; ++Mt)
      a[Mt] = ld_frag(embS + (Mt*16 + c16 + dlt)*136 + i0);
    #pragma unroll
    for (int ntl = 0; ntl < 4; ++ntl) {
      int nt = w*4 + ntl;
      bf16x8 bf = ld_frag(fragC + (kt*16 + nt)*512 + lane*8);
      #pragma unroll
      for (int Mt = 0; Mt < 4; ++Mt)
        acc[ntl][Mt] = mfma16(a[Mt], bf, acc[ntl][Mt]);
    }
  }

  #pragma unroll
  for (int ntl = 0; ntl < 4; ++ntl) {
    int ch = (w*4 + ntl)*16 + c16;
    float bias = bf2f(ch < 128 ? c1b[ch] : c2b[ch - 128]);
    float s0 = 0.f, s1 = 0.f;
    #pragma unroll
    for (int Mt = 0; Mt < 4; ++Mt) {
      #pragma unroll
      for (int r = 0; r < 4; ++r) {
        float v = acc[ntl][Mt][r] + bias;
        int t = t0 + Mt*16 + q*4 + r;
        y[((size_t)b*512 + t)*256 + ch] = f2bf(v);
        s0 += v; s1 += v*v;
      }
    }
    s0 += __shfl_xor(s0, 16); s0 += __shfl_xor(s0, 32);
    s1 += __shfl_xor(s1, 16); s1 += __shfl_xor(s1, 32);
    if (q == 0) { atomicAdd(&bnbuf[ch], s0); atomicAdd(&bnbuf[256 + ch], s1); }
  }
}

// ---------------------------------------------------------------------------
__global__ void k_bn(const uint16_t* __restrict__ gamma,
                     const uint16_t* __restrict__ beta,
                     float* __restrict__ bnbuf)
{
  int c = threadIdx.x;
  const float inv = 1.f / 131072.f;
  float mean = bnbuf[c] * inv;
  float var  = fmaxf(bnbuf[256 + c] * inv - mean*mean, 0.f);
  float sc   = bf2f(gamma[c]) * rsqrtf(var + 1e-5f);
  bnbuf[512 + c] = sc;
  bnbuf[768 + c] = bf2f(beta[c]) - mean * sc;
}

// ---------------------------------------------------------------------------
__global__ __launch_bounds__(256) void k_gx(
    const uint16_t* __restrict__ y, const float* __restrict__ bnbuf,
    const uint16_t* __restrict__ fragI, const uint16_t* __restrict__ bih,
    const uint16_t* __restrict__ bhh, uint16_t* __restrict__ gx, int tbase)
{
  __shared__ __align__(16) uint16_t aS[16384];
  int Mblk = blockIdx.x, Nblk = blockIdx.y;
  int tl = Mblk >> 2;
  int b0 = (Mblk & 3) * 64;
  int t = tbase + tl;
  int tid = threadIdx.x, lane = tid & 63, w = tid >> 6;
  int q = lane >> 4, c16 = lane & 15;

  for (int s = tid; s < 2048; s += 256) {
    int row = s >> 5, seg = s & 31;
    union { int4 i; uint16_t u[8]; } vv, oo;
    vv.i = *(const int4*)(y + ((size_t)(b0 + row)*512 + t)*256 + seg*8);
    #pragma unroll
    for (int j = 0; j < 8; ++j) {
      int ch = seg*8 + j;
      float f = bf2f(vv.u[j]) * bnbuf[512 + ch] + bnbuf[768 + ch];
      oo.u[j] = f2bf(fmaxf(f, 0.f));
    }
    int Mt = row >> 4, mL = row & 15, kt2 = seg >> 2, qq = seg & 3;
    *(int4*)(aS + ((Mt*8 + kt2)*64 + qq*16 + mL)*8) = oo.i;
  }
  __syncthreads();

  f32x4 acc[4][4];
  #pragma unroll
  for (int ntl = 0; ntl < 4; ++ntl) {
    int n = (Nblk*16 + w*4 + ntl)*16 + c16;
    float bias = bf2f(bih[n]) + bf2f(bhh[n]);
    #pragma unroll
    for (int Mt = 0; Mt < 4; ++Mt) acc[ntl][Mt] = (f32x4){bias,bias,bias,bias};
  }
  #pragma unroll
  for (int kt = 0; kt < 8; ++kt) {
    bf16x8 a[4];
    #pragma unroll
    for (int Mt = 0; Mt < 4; ++Mt)
      a[Mt] = ld_frag(aS + ((Mt*8 + kt)*64 + lane)*8);
    #pragma unroll
    for (int ntl = 0; ntl < 4; ++ntl) {
      int nt = Nblk*16 + w*4 + ntl;
      bf16x8 bf = ld_frag(fragI + ((size_t)(nt*8 + kt))*512 + lane*8);
      #pragma unroll
      for (int Mt = 0; Mt < 4; ++Mt)
        acc[ntl][Mt] = mfma16(a[Mt], bf, acc[ntl][Mt]);
    }
  }
  #pragma unroll
  for (int ntl = 0; ntl < 4; ++ntl) {
    int nt = Nblk*16 + w*4 + ntl;
    #pragma unroll
    for (int Mt = 0; Mt < 4; ++Mt) {
      int bg = (Mblk & 3)*4 + Mt;
      uint32_t lo = (uint32_t)f2bf(acc[ntl][Mt][0]) | ((uint32_t)f2bf(acc[ntl][Mt][1]) << 16);
      uint32_t hi = (uint32_t)f2bf(acc[ntl][Mt][2]) | ((uint32_t)f2bf(acc[ntl][Mt][3]) << 16);
      uint2 vv = {lo, hi};
      *(uint2*)(gx + ((size_t)(tl*16 + bg))*16384 + nt*256 + lane*4) = vv;
    }
  }
}

// ---------------------------------------------------------------------------
// k_lstm v4: 16 blocks x 512 threads (8 waves, 2/SIMD, 256-VGPR cap).
// Block bg owns batch rows [16bg,16bg+16). Wave w owns units [32w,32w+32):
// gate tiles ntg = {2w+p, 16+2w+p, 32+2w+p, 48+2w+p} (p=0,1). w_hh resident
// as fp8 e4m3 x16 (breg 128 VGPR). h stored in LDS as interleaved
// [H|L] byte pairs (H=fp8(16h), L=fp8(16*(16h-dec(H)))); two MFMA chains;
// g = gx + acc1/256 + acc2/4096. gx staged to LDS dbuf via global_load_lds.
// ---------------------------------------------------------------------------
__device__ __forceinline__ float gxf(uint2 v, int r){
  uint32_t d = (r < 2) ? v.x : v.y;
  return bf2f((r & 1) ? (uint16_t)(d >> 16) : (uint16_t)(d & 0xffffu));
}

__global__ __launch_bounds__(512, 2) void k_lstm(
    const uint16_t* __restrict__ gx, const uint2* __restrict__ fragH8,
    const int* __restrict__ lengths, float* __restrict__ wsHf,
    float* __restrict__ wsC, float* __restrict__ hn,
    int tbase, int tcount, int last)
{
  __shared__ __align__(16) uint8_t hS[2][8192];
  __shared__ __align__(16) uint8_t gxS[2][32768];
  int bg = blockIdx.x;
  int tid = threadIdx.x, lane = tid & 63, w = tid >> 6;   // w = 0..7
  int q = lane >> 4, c16 = lane & 15;

  int li[4];
  #pragma unroll
  for (int r = 0; r < 4; ++r) li[r] = lengths[bg*16 + q*4 + r];
  int Tmax = lengths[bg*16];                   // lengths sorted descending

  int ntg[8];
  uint2 breg[8][8];                            // w_hh fp8, fully resident
  #pragma unroll
  for (int gp = 0; gp < 8; ++gp) {
    ntg[gp] = (gp >> 1)*16 + 2*w + (gp & 1);
    #pragma unroll
    for (int kt = 0; kt < 8; ++kt)
      breg[gp][kt] = fragH8[(ntg[gp]*8 + kt)*64 + lane];
  }

  int ub[2], wb[2], jb[2];
  #pragma unroll
  for (int p = 0; p < 2; ++p) {
    int u = 32*w + p*16 + c16;
    ub[p] = u;
    wb[p] = ((u >> 5)*4 + ((u >> 3) & 3))*16;  // cell base (kt,qq)
    jb[p] = u & 7;
  }

  float cr[2][4], hr[2][4];
  #pragma unroll
  for (int p = 0; p < 2; ++p)
    #pragma unroll
    for (int r = 0; r < 4; ++r) {
      cr[p][r] = wsC [(bg*16 + q*4 + r)*256 + ub[p]];
      hr[p][r] = wsHf[(bg*16 + q*4 + r)*256 + ub[p]];
    }

  // initial hS[0] from carry
  #pragma unroll
  for (int p = 0; p < 2; ++p)
    #pragma unroll
    for (int r = 0; r < 4; ++r)
      emit_h(&hS[0][0], wb[p], q*4 + r, jb[p], hr[p][r]);

  // initial gx slab -> gxS[0]
  {
    const uint8_t* gsrc = (const uint8_t*)(gx + (size_t)bg*16384);
    #pragma unroll
    for (int i = 0; i < 4; ++i) {
      int off = w*4096 + i*1024 + lane*16;
      dma16(gsrc + off, &gxS[0][off]);
    }
  }
  __syncthreads();

  int cur = 0;
  int tEnd = min(tbase + tcount, Tmax);
  const float C1 = 1.f/256.f, C2 = 1.f/4096.f;

  for (int t = tbase; t < tEnd; ++t) {
    // stage next step's gx into gxS[cur^1]
    {
      int tn = (t + 1 < tEnd) ? (t + 1 - tbase) : (t - tbase);
      const uint8_t* gsrc = (const uint8_t*)(gx + ((size_t)(tn*16 + bg))*16384);
      #pragma unroll
      for (int i = 0; i < 4; ++i) {
        int off = w*4096 + i*1024 + lane*16;
        dma16(gsrc + off, &gxS[cur ^ 1][off]);
      }
    }

    f32x4 acc1[8], acc2[8];
    #pragma unroll
    for (int gp = 0; gp < 8; ++gp) {
      acc1[gp] = (f32x4){0.f,0.f,0.f,0.f};
      acc2[gp] = (f32x4){0.f,0.f,0.f,0.f};
    }

    #pragma unroll
    for (int kt = 0; kt < 8; ++kt) {
      int4 hl = *(const int4*)(&hS[cur][((kt*4 + q)*16 + c16)*16]);
      i64_t ahi = mk64(__builtin_amdgcn_perm((uint32_t)hl.y, (uint32_t)hl.x, 0x06040200u),
                       __builtin_amdgcn_perm((uint32_t)hl.w, (uint32_t)hl.z, 0x06040200u));
      i64_t alo = mk64(__builtin_amdgcn_perm((uint32_t)hl.y, (uint32_t)hl.x, 0x07050301u),
                       __builtin_amdgcn_perm((uint32_t)hl.w, (uint32_t)hl.z, 0x07050301u));
      #pragma unroll
      for (int gp = 0; gp < 8; ++gp) {
        i64_t b = mk64(breg[gp][kt].x, breg[gp][kt].y);
        acc1[gp] = mfma8(ahi, b, acc1[gp]);
        acc2[gp] = mfma8(alo, b, acc2[gp]);
      }
    }

    // gx for this step from LDS
    uint2 gg[8];
    #pragma unroll
    for (int gp = 0; gp < 8; ++gp)
      gg[gp] = *(const uint2*)(&gxS[cur][(ntg[gp]*64 + lane)*8]);

    #pragma unroll
    for (int r = 0; r < 4; ++r) {
      bool upd = (t < li[r]);
      #pragma unroll
      for (int p = 0; p < 2; ++p) {
        float gi = gxf(gg[0+p], r) + acc1[0+p][r]*C1 + acc2[0+p][r]*C2;
        float gf = gxf(gg[2+p], r) + acc1[2+p][r]*C1 + acc2[2+p][r]*C2;
        float g2 = gxf(gg[4+p], r) + acc1[4+p][r]*C1 + acc2[4+p][r]*C2;
        float go = gxf(gg[6+p], r) + acc1[6+p][r]*C1 + acc2[6+p][r]*C2;
        float cn = sigm(gf)*cr[p][r] + sigm(gi)*tanh_(g2);
        float hw = sigm(go)*tanh_(cn);
        cn = upd ? cn : cr[p][r];
        hw = upd ? hw : hr[p][r];
        cr[p][r] = cn; hr[p][r] = hw;
        emit_h(&hS[cur ^ 1][0], wb[p], q*4 + r, jb[p], hw);
      }
    }

    __syncthreads();
    cur ^= 1;
  }

  #pragma unroll
  for (int p = 0; p < 2; ++p)
    #pragma unroll
    for (int r = 0; r < 4; ++r) {
      wsC [(bg*16 + q*4 + r)*256 + ub[p]] = cr[p][r];
      wsHf[(bg*16 + q*4 + r)*256 + ub[p]] = hr[p][r];
    }

  if (last) {
    #pragma unroll
    for (int p = 0; p < 2; ++p)
      #pragma unroll
      for (int r = 0; r < 4; ++r)
        hn[(bg*16 + q*4 + r)*256 + ub[p]] = hr[p][r];
  }
}

// ---------------------------------------------------------------------------
__global__ __launch_bounds__(256) void k_attn(
    const uint16_t* __restrict__ y, const float* __restrict__ hn,
    const uint16_t* __restrict__ linw, const uint16_t* __restrict__ linb,
    void* __restrict__ outv, const int* __restrict__ flag)
{
  __shared__ float hnS[256];
  __shared__ float attnS[512];
  int b = blockIdx.x;
  int tid = threadIdx.x, lane = tid & 63, w = tid >> 6;
  int isb = *flag;
  hnS[tid] = hn[b*256 + tid];
  __syncthreads();
  for (int t = w; t < 512; t += 4) {
    uint2 d = *(const uint2*)(y + ((size_t)b*512 + t)*256 + lane*4);
    float s = bf2f((uint16_t)(d.x & 0xffffu)) * hnS[lane*4 + 0]
            + bf2f((uint16_t)(d.x >> 16))     * hnS[lane*4 + 1]
            + bf2f((uint16_t)(d.y & 0xffffu)) * hnS[lane*4 + 2]
            + bf2f((uint16_t)(d.y >> 16))     * hnS[lane*4 + 3];
    #pragma unroll
    for (int off = 32; off >= 1; off >>= 1) s += __shfl_xor(s, off);
    if (lane == 0) attnS[t] = s * 0.0625f;     // 1/sqrt(256)
  }
  __syncthreads();
  float acc = 0.f;
  #pragma unroll 4
  for (int t = 0; t < 512; ++t)
    acc += attnS[t] * bf2f(y[((size_t)b*512 + t)*256 + tid]);
  if (isb) ((uint16_t*)outv)[7936 + b*256 + tid] = f2bf(acc);
  else     ((float*)outv)[7936 + b*256 + tid] = acc;
  if (tid < 31) {
    float a2 = bf2f(linb[tid]);
    for (int k = 0; k < 256; ++k) a2 += hnS[k] * bf2f(linw[tid*256 + k]);
    if (isb) ((uint16_t*)outv)[b*31 + tid] = f2bf(a2);
    else     ((float*)outv)[b*31 + tid] = a2;
  }
}

// ---------------------------------------------------------------------------
extern "C" void kernel_launch(void* const* d_in, const int* in_sizes, int n_in,
                              void* d_out, int out_size, void* d_ws, size_t ws_size,
                              hipStream_t stream)
{
  (void)in_sizes; (void)out_size;
  if (n_in < 15) return;
  const int* x   = (const int*)d_in[0];
  const int* len = (const int*)d_in[1];

  uint8_t* p = (uint8_t*)d_ws;
  auto take = [&](size_t n){ uint8_t* r = p; p += (n + 255) & ~(size_t)255; return r; };
  int*      flag  = (int*)take(256);
  uint16_t* c1bC  = (uint16_t*)take(256);
  uint16_t* c2bC  = (uint16_t*)take(256);
  uint16_t* bngC  = (uint16_t*)take(512);
  uint16_t* bnbC  = (uint16_t*)take(512);
  uint16_t* bihC  = (uint16_t*)take(2048);
  uint16_t* bhhC  = (uint16_t*)take(2048);
  uint16_t* linwC = (uint16_t*)take(15872);
  uint16_t* linbC = (uint16_t*)take(64);
  uint16_t* fragC = (uint16_t*)take(327680);
  uint16_t* fragI = (uint16_t*)take(524288);
  uint2*    fragH8= (uint2*)take(262144);
  float*    bnbuf = (float*)take(4096);
  float*    wsHf  = (float*)take(262144);
  float*    wsC   = (float*)take(262144);
  float*    hnbuf = (float*)take(262144);
  uint16_t* y     = (uint16_t*)take(67108864ull);
  uint16_t* gxb   = (uint16_t*)take(67108864ull);
  if ((size_t)(p - (uint8_t*)d_ws) > ws_size) return;

  // big converted tensors live inside gxb (dead before k_gx first writes it)
  uint16_t* etabC = gxb;
  uint16_t* c1wC  = (uint16_t*)((uint8_t*)gxb + 16u*1024*1024);
  uint16_t* c2wC  = (uint16_t*)((uint8_t*)gxb + 17u*1024*1024);
  uint16_t* wihC  = (uint16_t*)((uint8_t*)gxb + 18u*1024*1024);
  uint16_t* whhC  = (uint16_t*)((uint8_t*)gxb + 19u*1024*1024);

  k_sniff<<<1, 256, 0, stream>>>((const uint32_t*)d_in[2], flag);

  CvtArgs A;
  int c0 = 0;
  auto put = [&](int i, const void* s, uint16_t* d, int n){
    A.a[i].s = s; A.a[i].d = d; A.a[i].n = n; A.a[i].c0 = c0;
    c0 += (n + 4095) / 4096;
  };
  put(0,  d_in[2],  etabC, 6400000);
  put(1,  d_in[3],  c1wC,  49152);
  put(2,  d_in[4],  c1bC,  128);
  put(3,  d_in[5],  c2wC,  81920);
  put(4,  d_in[6],  c2bC,  128);
  put(5,  d_in[7],  bngC,  256);
  put(6,  d_in[8],  bnbC,  256);
  put(7,  d_in[9],  wihC,  262144);
  put(8,  d_in[10], whhC,  262144);
  put(9,  d_in[11], bihC,  1024);
  put(10, d_in[12], bhhC,  1024);
  put(11, d_in[13], linwC, 7936);
  put(12, d_in[14], linbC, 31);
  k_cvt<<<c0, 256, 0, stream>>>(A, flag);

  k_prep<<<512, 256, 0, stream>>>(c1wC, c2wC, wihC, whhC, fragC, fragI, fragH8,
                                  bnbuf, wsHf, wsC);
  k_conv<<<2048, 256, 0, stream>>>(x, etabC, fragC, c1bC, c2bC, y, bnbuf);
  k_bn<<<1, 256, 0, stream>>>(bngC, bnbC, bnbuf);
  for (int c = 0; c < 4; ++c) {
    k_gx<<<dim3(512, 4), 256, 0, stream>>>(y, bnbuf, fragI, bihC, bhhC, gxb, c*128);
    k_lstm<<<16, 512, 0, stream>>>(gxb, fragH8, len, wsHf, wsC, hnbuf,
                                   c*128, 128, (c == 3) ? 1 : 0);
  }
  k_attn<<<256, 256, 0, stream>>>(y, hnbuf, linwC, linbC, d_out, flag);
}

// Round 7
// 2742.345 us; speedup vs baseline: 1.5252x; 1.0652x over previous
//
#include <hip/hip_runtime.h>
#include <stdint.h>

// ---------------------------------------------------------------------------
// RNNClassifier pipeline for MI355X (gfx950). Dtype-agnostic input handling
// (sniffer + converter to bf16). Core pipeline (MFMA, f32 accum):
//  k_prep : conv/w_ih weights -> bf16 MFMA B-frags; w_hh -> fp8 e4m3 B-frags
//           scaled x16; zero carries.
//  k_conv : embedding gather + (conv3|conv5) as one K=640 im2col GEMM -> y
//  k_bn   : finalize BN scale/shift
//  k_gx   : gx = ReLU(BN(y)) @ w_ih^T + b_ih + b_hh, C-layout, SCALED x256
//           (v5: folded into the MFMA accumulator init in k_lstm)
//  k_lstm : v5: 16 blocks x 1024 thr (16 waves, 4/SIMD). Wave w owns 4 gate
//           tiles ntg=gp*16+w (unit u=w*16+c16, all 4 gates in-lane). w_hh
//           register-resident fp8 (64 VGPR/wave). h as split fp8 [H|L] in
//           LDS; two MFMA chains; g = acc1/256 + acc2/4096 with acc1
//           initialized from 256*gx. Fast path skips masking while
//           t < min(lengths) of the block. R6 (2 waves/SIMD) was
//           latency-bound at 4.8us/step (35% Mfma + 51% VALU per active CU).
//  k_attn : attn/attn_out/logits epilogue
//
// MFMA 16x16x32 layouts (bf16 verified m89/m120; fp8 same pattern, bytes):
//   A: lane holds A[m=lane&15][k=(lane>>4)*8+j], j=0..7
//   B: lane holds B[k=(lane>>4)*8+j][n=lane&15]
//   C/D: lane holds D[m=(lane>>4)*4+r][n=lane&15], r=0..3
// ---------------------------------------------------------------------------

typedef __bf16 bf16x8 __attribute__((ext_vector_type(8)));
typedef float  f32x4  __attribute__((ext_vector_type(4)));

__device__ __forceinline__ float bf2f(uint16_t h){
  union { uint32_t u; float f; } v; v.u = ((uint32_t)h) << 16; return v.f;
}
__device__ __forceinline__ uint16_t f2bf(float f){
  union { float f; uint32_t u; } v; v.f = f;
  return (uint16_t)((v.u + 0x7FFFu + ((v.u >> 16) & 1u)) >> 16);
}
__device__ __forceinline__ bf16x8 ld_frag(const uint16_t* p){
  union { int4 i; bf16x8 b; } u; u.i = *(const int4*)p; return u.b;
}
__device__ __forceinline__ f32x4 mfma16(bf16x8 a, bf16x8 b, f32x4 c){
  return __builtin_amdgcn_mfma_f32_16x16x32_bf16(a, b, c, 0, 0, 0);
}
__device__ __forceinline__ float sigm(float x){
  return __builtin_amdgcn_rcpf(1.f + __expf(-x));
}
__device__ __forceinline__ float tanh_(float x){
  return 2.f * __builtin_amdgcn_rcpf(1.f + __expf(-2.f * x)) - 1.f;
}

typedef long i64_t;
__device__ __forceinline__ i64_t mk64(uint32_t lo, uint32_t hi){
  union { uint2 u; i64_t l; } t; t.u = make_uint2(lo, hi); return t.l;
}
__device__ __forceinline__ f32x4 mfma8(i64_t a, i64_t b, f32x4 c){
  return __builtin_amdgcn_mfma_f32_16x16x32_fp8_fp8(a, b, c, 0, 0, 0);
}
__device__ __forceinline__ void dma16(const void* g, void* l){
  __builtin_amdgcn_global_load_lds(
      (const __attribute__((address_space(1))) uint32_t*)g,
      (__attribute__((address_space(3))) uint32_t*)l, 16, 0, 0);
}
// write h as [H|L] byte pair into A-frag LDS layout
__device__ __forceinline__ void emit_h(uint8_t* buf, int cellbase, int m,
                                       int j, float h){
  float h16 = h * 16.f;
  int p1 = __builtin_amdgcn_cvt_pk_fp8_f32(h16, h16, 0, false);
  float dec = __builtin_amdgcn_cvt_f32_fp8(p1, 0);
  float r16 = (h16 - dec) * 16.f;
  int p2 = __builtin_amdgcn_cvt_pk_fp8_f32(r16, r16, 0, false);
  *(uint16_t*)(buf + (cellbase + m)*16 + 2*j) =
      (uint16_t)((p1 & 0xff) | ((p2 & 0xff) << 8));
}

// ---------------------------------------------------------------------------
__global__ __launch_bounds__(256) void k_sniff(const uint32_t* __restrict__ e,
                                               int* __restrict__ flag)
{
  __shared__ int cnt;
  int tid = threadIdx.x;
  if (tid == 0) cnt = 0;
  __syncthreads();
  uint32_t u = e[tid];
  uint32_t ex = (u >> 7) & 0xFFu;
  if (ex >= 0x60u && ex <= 0x7Eu) atomicAdd(&cnt, 1);
  __syncthreads();
  if (tid == 0) flag[0] = (cnt >= 192) ? 1 : 0;
}

// ---------------------------------------------------------------------------
struct CvtDesc { const void* s; uint16_t* d; int n; int c0; };
struct CvtArgs { CvtDesc a[13]; };

__global__ __launch_bounds__(256) void k_cvt(CvtArgs A, const int* __restrict__ flag)
{
  int ch = blockIdx.x;
  int i = 0;
  #pragma unroll
  for (int k = 1; k < 13; ++k) if (ch >= A.a[k].c0) i = k;
  const void* s = A.a[i].s;
  uint16_t*   d = A.a[i].d;
  int n = A.a[i].n;
  int base = (ch - A.a[i].c0) * 4096 + threadIdx.x;
  int isb = *flag;
  #pragma unroll 4
  for (int r = 0; r < 16; ++r) {
    int idx = base + r * 256;
    if (idx < n)
      d[idx] = isb ? ((const uint16_t*)s)[idx] : f2bf(((const float*)s)[idx]);
  }
}

// ---------------------------------------------------------------------------
__global__ __launch_bounds__(256) void k_prep(
    const uint16_t* __restrict__ c1w, const uint16_t* __restrict__ c2w,
    const uint16_t* __restrict__ wih, const uint16_t* __restrict__ whh,
    uint16_t* __restrict__ fragC, uint16_t* __restrict__ fragI,
    uint2* __restrict__ fragH8, float* __restrict__ bnbuf,
    float* __restrict__ wsHf, float* __restrict__ wsC)
{
  int g = blockIdx.x * 256 + threadIdx.x;
  if (g < 20480) {                       // conv B fragments (320 tiles)
    int tile = g >> 6, lane = g & 63;
    int kt = tile >> 4, nt = tile & 15;
    int q = lane >> 4, c16 = lane & 15;
    int dlt = kt >> 2;
    int o = nt * 16 + c16;
    union { int4 i; uint16_t u[8]; } v;
    #pragma unroll
    for (int j = 0; j < 8; ++j) {
      int i = (kt & 3) * 32 + q * 8 + j;
      uint16_t val = 0;
      if (o < 128) { int k = dlt - 1; if (k >= 0 && k < 3) val = c1w[(o*128 + i)*3 + k]; }
      else         { int k = dlt;     if (k < 5)           val = c2w[((o-128)*128 + i)*5 + k]; }
      v.u[j] = val;
    }
    *(int4*)(fragC + tile * 512 + lane * 8) = v.i;
  } else if (g < 53248) {                // w_ih bf16 fragments (512 tiles)
    int gg = g - 20480;
    int tile = gg >> 6, lane = gg & 63;
    int nt = tile >> 3, kt = tile & 7;
    int q = lane >> 4, c16 = lane & 15;
    *(int4*)(fragI + tile * 512 + lane * 8) =
        *(const int4*)(wih + (nt*16 + c16)*256 + kt*32 + q*8);
  } else if (g < 86016) {                // w_hh fp8 fragments (x16 scale)
    int gg = g - 53248;
    int tile = gg >> 6, lane = gg & 63;
    int nt = tile >> 3, kt = tile & 7;
    int q = lane >> 4, c16 = lane & 15;
    const uint16_t* src = whh + (nt*16 + c16)*256 + kt*32 + q*8;
    float f[8];
    #pragma unroll
    for (int j = 0; j < 8; ++j) f[j] = bf2f(src[j]) * 16.f;
    int lo = __builtin_amdgcn_cvt_pk_fp8_f32(f[0], f[1], 0, false);
    lo     = __builtin_amdgcn_cvt_pk_fp8_f32(f[2], f[3], lo, true);
    int hi = __builtin_amdgcn_cvt_pk_fp8_f32(f[4], f[5], 0, false);
    hi     = __builtin_amdgcn_cvt_pk_fp8_f32(f[6], f[7], hi, true);
    fragH8[tile*64 + lane] = make_uint2((uint32_t)lo, (uint32_t)hi);
  } else if (g < 102400) {               // zero wsHf (65536 f32)
    ((int4*)wsHf)[g - 86016] = make_int4(0,0,0,0);
  } else if (g < 118784) {               // zero wsC (65536 f32)
    ((int4*)wsC)[g - 102400] = make_int4(0,0,0,0);
  } else if (g < 118912) {               // zero bn sums (512 f32)
    ((int4*)bnbuf)[g - 118784] = make_int4(0,0,0,0);
  }
}

// ---------------------------------------------------------------------------
__global__ __launch_bounds__(256) void k_conv(
    const int* __restrict__ x, const uint16_t* __restrict__ etab,
    const uint16_t* __restrict__ fragC,
    const uint16_t* __restrict__ c1b, const uint16_t* __restrict__ c2b,
    uint16_t* __restrict__ y, float* __restrict__ bnbuf)
{
  __shared__ __align__(16) uint16_t embS[68 * 136];
  int blk = blockIdx.x;
  int b = blk >> 3, t0 = (blk & 7) * 64;
  int tid = threadIdx.x;
  int lane = tid & 63, w = tid >> 6;
  int q = lane >> 4, c16 = lane & 15;

  for (int s = tid; s < 1088; s += 256) {      // 68 rows x 16 segs of 16B
    int r = s >> 4, seg = s & 15;
    int t = t0 - 2 + r;
    int4 val = make_int4(0,0,0,0);
    if (t >= 0 && t < 512) {
      int idx = x[b*512 + t];
      val = *(const int4*)(etab + (size_t)idx*128 + seg*8);
    }
    *(int4*)(embS + r*136 + seg*8) = val;
  }
  __syncthreads();

  f32x4 acc[4][4];
  #pragma unroll
  for (int i = 0; i < 4; ++i)
    #pragma unroll
    for (int j = 0; j < 4; ++j) acc[i][j] = (f32x4){0.f,0.f,0.f,0.f};

  #pragma unroll 4
  for (int kt = 0; kt < 20; ++kt) {
    int dlt = kt >> 2;
    int i0 = (kt & 3)*32 + q*8;
    bf16x8 a[4];
    #pragma unroll
    for (int Mt = 0; Mt < 4; ++Mt)
      a[Mt] = ld_frag(embS + (Mt*16 + c16 + dlt)*136 + i0);
    #pragma unroll
    for (int ntl = 0; ntl < 4; ++ntl) {
      int nt = w*4 + ntl;
      bf16x8 bf = ld_frag(fragC + (kt*16 + nt)*512 + lane*8);
      #pragma unroll
      for (int Mt = 0; Mt < 4; ++Mt)
        acc[ntl][Mt] = mfma16(a[Mt], bf, acc[ntl][Mt]);
    }
  }

  #pragma unroll
  for (int ntl = 0; ntl < 4; ++ntl) {
    int ch = (w*4 + ntl)*16 + c16;
    float bias = bf2f(ch < 128 ? c1b[ch] : c2b[ch - 128]);
    float s0 = 0.f, s1 = 0.f;
    #pragma unroll
    for (int Mt = 0; Mt < 4; ++Mt) {
      #pragma unroll
      for (int r = 0; r < 4; ++r) {
        float v = acc[ntl][Mt][r] + bias;
        int t = t0 + Mt*16 + q*4 + r;
        y[((size_t)b*512 + t)*256 + ch] = f2bf(v);
        s0 += v; s1 += v*v;
      }
    }
    s0 += __shfl_xor(s0, 16); s0 += __shfl_xor(s0, 32);
    s1 += __shfl_xor(s1, 16); s1 += __shfl_xor(s1, 32);
    if (q == 0) { atomicAdd(&bnbuf[ch], s0); atomicAdd(&bnbuf[256 + ch], s1); }
  }
}

// ---------------------------------------------------------------------------
__global__ void k_bn(const uint16_t* __restrict__ gamma,
                     const uint16_t* __restrict__ beta,
                     float* __restrict__ bnbuf)
{
  int c = threadIdx.x;
  const float inv = 1.f / 131072.f;
  float mean = bnbuf[c] * inv;
  float var  = fmaxf(bnbuf[256 + c] * inv - mean*mean, 0.f);
  float sc   = bf2f(gamma[c]) * rsqrtf(var + 1e-5f);
  bnbuf[512 + c] = sc;
  bnbuf[768 + c] = bf2f(beta[c]) - mean * sc;
}

// ---------------------------------------------------------------------------
// k_gx: output is 256*g (exact pow2 scale; consumed as MFMA acc init).
// ---------------------------------------------------------------------------
__global__ __launch_bounds__(256) void k_gx(
    const uint16_t* __restrict__ y, const float* __restrict__ bnbuf,
    const uint16_t* __restrict__ fragI, const uint16_t* __restrict__ bih,
    const uint16_t* __restrict__ bhh, uint16_t* __restrict__ gx, int tbase)
{
  __shared__ __align__(16) uint16_t aS[16384];
  int Mblk = blockIdx.x, Nblk = blockIdx.y;
  int tl = Mblk >> 2;
  int b0 = (Mblk & 3) * 64;
  int t = tbase + tl;
  int tid = threadIdx.x, lane = tid & 63, w = tid >> 6;
  int q = lane >> 4, c16 = lane & 15;

  for (int s = tid; s < 2048; s += 256) {
    int row = s >> 5, seg = s & 31;
    union { int4 i; uint16_t u[8]; } vv, oo;
    vv.i = *(const int4*)(y + ((size_t)(b0 + row)*512 + t)*256 + seg*8);
    #pragma unroll
    for (int j = 0; j < 8; ++j) {
      int ch = seg*8 + j;
      float f = bf2f(vv.u[j]) * bnbuf[512 + ch] + bnbuf[768 + ch];
      oo.u[j] = f2bf(fmaxf(f, 0.f));
    }
    int Mt = row >> 4, mL = row & 15, kt2 = seg >> 2, qq = seg & 3;
    *(int4*)(aS + ((Mt*8 + kt2)*64 + qq*16 + mL)*8) = oo.i;
  }
  __syncthreads();

  f32x4 acc[4][4];
  #pragma unroll
  for (int ntl = 0; ntl < 4; ++ntl) {
    int n = (Nblk*16 + w*4 + ntl)*16 + c16;
    float bias = bf2f(bih[n]) + bf2f(bhh[n]);
    #pragma unroll
    for (int Mt = 0; Mt < 4; ++Mt) acc[ntl][Mt] = (f32x4){bias,bias,bias,bias};
  }
  #pragma unroll
  for (int kt = 0; kt < 8; ++kt) {
    bf16x8 a[4];
    #pragma unroll
    for (int Mt = 0; Mt < 4; ++Mt)
      a[Mt] = ld_frag(aS + ((Mt*8 + kt)*64 + lane)*8);
    #pragma unroll
    for (int ntl = 0; ntl < 4; ++ntl) {
      int nt = Nblk*16 + w*4 + ntl;
      bf16x8 bf = ld_frag(fragI + ((size_t)(nt*8 + kt))*512 + lane*8);
      #pragma unroll
      for (int Mt = 0; Mt < 4; ++Mt)
        acc[ntl][Mt] = mfma16(a[Mt], bf, acc[ntl][Mt]);
    }
  }
  #pragma unroll
  for (int ntl = 0; ntl < 4; ++ntl) {
    int nt = Nblk*16 + w*4 + ntl;
    #pragma unroll
    for (int Mt = 0; Mt < 4; ++Mt) {
      int bg = (Mblk & 3)*4 + Mt;
      uint32_t lo = (uint32_t)f2bf(acc[ntl][Mt][0]*256.f) | ((uint32_t)f2bf(acc[ntl][Mt][1]*256.f) << 16);
      uint32_t hi = (uint32_t)f2bf(acc[ntl][Mt][2]*256.f) | ((uint32_t)f2bf(acc[ntl][Mt][3]*256.f) << 16);
      uint2 vv = {lo, hi};
      *(uint2*)(gx + ((size_t)(tl*16 + bg))*16384 + nt*256 + lane*4) = vv;
    }
  }
}

// ---------------------------------------------------------------------------
// k_lstm v5: 16 blocks x 1024 threads (16 waves, 4/SIMD). Block bg owns
// batch rows [16bg,16bg+16). Wave w owns units [16w,16w+16): one gate tile
// per gate group, ntg[gp]=gp*16+w -> unit u=w*16+c16, all 4 gates in-lane.
// breg fp8 = 64 VGPR/wave, fully resident. Two MFMA chains on split-fp8 h;
// acc1 initialized from 256*gx (LDS, staged by global_load_lds dbuf);
// g = acc1/256 + acc2/4096.
// ---------------------------------------------------------------------------
__global__ __launch_bounds__(1024, 1) void k_lstm(
    const uint16_t* __restrict__ gx, const uint2* __restrict__ fragH8,
    const int* __restrict__ lengths, float* __restrict__ wsHf,
    float* __restrict__ wsC, float* __restrict__ hn,
    int tbase, int tcount, int last)
{
  __shared__ __align__(16) uint8_t hS[2][8192];
  __shared__ __align__(16) uint8_t gxS[2][32768];
  int bg = blockIdx.x;
  int tid = threadIdx.x, lane = tid & 63, w = tid >> 6;   // w = 0..15
  int q = lane >> 4, c16 = lane & 15;
  int u = w*16 + c16;

  int li[4];
  #pragma unroll
  for (int r = 0; r < 4; ++r) li[r] = lengths[bg*16 + q*4 + r];
  int Tmax  = lengths[bg*16];                  // lengths sorted descending
  int liMin = lengths[bg*16 + 15];

  int ntg[4];
  uint2 breg[4][8];                            // w_hh fp8, fully resident
  #pragma unroll
  for (int gp = 0; gp < 4; ++gp) {
    ntg[gp] = gp*16 + w;
    #pragma unroll
    for (int kt = 0; kt < 8; ++kt)
      breg[gp][kt] = fragH8[(ntg[gp]*8 + kt)*64 + lane];
  }

  int wb = ((u >> 5)*4 + ((u >> 3) & 3))*16;   // h cell base
  int jb = u & 7;

  float cr[4], hr[4];
  #pragma unroll
  for (int r = 0; r < 4; ++r) {
    cr[r] = wsC [(bg*16 + q*4 + r)*256 + u];
    hr[r] = wsHf[(bg*16 + q*4 + r)*256 + u];
  }

  // initial hS[0] from carry
  #pragma unroll
  for (int r = 0; r < 4; ++r)
    emit_h(&hS[0][0], wb, q*4 + r, jb, hr[r]);

  // initial gx slab -> gxS[0]
  {
    const uint8_t* gsrc = (const uint8_t*)(gx + (size_t)bg*16384);
    #pragma unroll
    for (int i = 0; i < 2; ++i) {
      int off = w*2048 + i*1024 + lane*16;
      dma16(gsrc + off, &gxS[0][off]);
    }
  }
  __syncthreads();

  int cur = 0;
  int tEnd = min(tbase + tcount, Tmax);
  const float C1 = 1.f/256.f, C2 = 1.f/4096.f;

  for (int t = tbase; t < tEnd; ++t) {
    // stage next step's gx into gxS[cur^1]
    {
      int tn = (t + 1 < tEnd) ? (t + 1 - tbase) : (t - tbase);
      const uint8_t* gsrc = (const uint8_t*)(gx + ((size_t)(tn*16 + bg))*16384);
      #pragma unroll
      for (int i = 0; i < 2; ++i) {
        int off = w*2048 + i*1024 + lane*16;
        dma16(gsrc + off, &gxS[cur ^ 1][off]);
      }
    }

    // acc1 init from 256*gx (LDS); acc2 zero
    f32x4 acc1[4], acc2[4];
    #pragma unroll
    for (int gp = 0; gp < 4; ++gp) {
      uint2 gg = *(const uint2*)(&gxS[cur][(ntg[gp]*64 + lane)*8]);
      acc1[gp][0] = bf2f((uint16_t)(gg.x & 0xffffu));
      acc1[gp][1] = bf2f((uint16_t)(gg.x >> 16));
      acc1[gp][2] = bf2f((uint16_t)(gg.y & 0xffffu));
      acc1[gp][3] = bf2f((uint16_t)(gg.y >> 16));
      acc2[gp] = (f32x4){0.f,0.f,0.f,0.f};
    }

    #pragma unroll
    for (int kt = 0; kt < 8; ++kt) {
      int4 hl = *(const int4*)(&hS[cur][((kt*4 + q)*16 + c16)*16]);
      i64_t ahi = mk64(__builtin_amdgcn_perm((uint32_t)hl.y, (uint32_t)hl.x, 0x06040200u),
                       __builtin_amdgcn_perm((uint32_t)hl.w, (uint32_t)hl.z, 0x06040200u));
      i64_t alo = mk64(__builtin_amdgcn_perm((uint32_t)hl.y, (uint32_t)hl.x, 0x07050301u),
                       __builtin_amdgcn_perm((uint32_t)hl.w, (uint32_t)hl.z, 0x07050301u));
      #pragma unroll
      for (int gp = 0; gp < 4; ++gp) {
        i64_t b = mk64(breg[gp][kt].x, breg[gp][kt].y);
        acc1[gp] = mfma8(ahi, b, acc1[gp]);
        acc2[gp] = mfma8(alo, b, acc2[gp]);
      }
    }

    if (t < liMin) {                            // fast path: no masking
      #pragma unroll
      for (int r = 0; r < 4; ++r) {
        float gi = acc1[0][r]*C1 + acc2[0][r]*C2;
        float gf = acc1[1][r]*C1 + acc2[1][r]*C2;
        float g2 = acc1[2][r]*C1 + acc2[2][r]*C2;
        float go = acc1[3][r]*C1 + acc2[3][r]*C2;
        float cn = sigm(gf)*cr[r] + sigm(gi)*tanh_(g2);
        float hw = sigm(go)*tanh_(cn);
        cr[r] = cn; hr[r] = hw;
        emit_h(&hS[cur ^ 1][0], wb, q*4 + r, jb, hw);
      }
    } else {
      #pragma unroll
      for (int r = 0; r < 4; ++r) {
        bool upd = (t < li[r]);
        float gi = acc1[0][r]*C1 + acc2[0][r]*C2;
        float gf = acc1[1][r]*C1 + acc2[1][r]*C2;
        float g2 = acc1[2][r]*C1 + acc2[2][r]*C2;
        float go = acc1[3][r]*C1 + acc2[3][r]*C2;
        float cn = sigm(gf)*cr[r] + sigm(gi)*tanh_(g2);
        float hw = sigm(go)*tanh_(cn);
        cn = upd ? cn : cr[r];
        hw = upd ? hw : hr[r];
        cr[r] = cn; hr[r] = hw;
        emit_h(&hS[cur ^ 1][0], wb, q*4 + r, jb, hw);
      }
    }

    __syncthreads();
    cur ^= 1;
  }

  #pragma unroll
  for (int r = 0; r < 4; ++r) {
    wsC [(bg*16 + q*4 + r)*256 + u] = cr[r];
    wsHf[(bg*16 + q*4 + r)*256 + u] = hr[r];
  }

  if (last) {
    #pragma unroll
    for (int r = 0; r < 4; ++r)
      hn[(bg*16 + q*4 + r)*256 + u] = hr[r];
  }
}

// ---------------------------------------------------------------------------
__global__ __launch_bounds__(256) void k_attn(
    const uint16_t* __restrict__ y, const float* __restrict__ hn,
    const uint16_t* __restrict__ linw, const uint16_t* __restrict__ linb,
    void* __restrict__ outv, const int* __restrict__ flag)
{
  __shared__ float hnS[256];
  __shared__ float attnS[512];
  int b = blockIdx.x;
  int tid = threadIdx.x, lane = tid & 63, w = tid >> 6;
  int isb = *flag;
  hnS[tid] = hn[b*256 + tid];
  __syncthreads();
  for (int t = w; t < 512; t += 4) {
    uint2 d = *(const uint2*)(y + ((size_t)b*512 + t)*256 + lane*4);
    float s = bf2f((uint16_t)(d.x & 0xffffu)) * hnS[lane*4 + 0]
            + bf2f((uint16_t)(d.x >> 16))     * hnS[lane*4 + 1]
            + bf2f((uint16_t)(d.y & 0xffffu)) * hnS[lane*4 + 2]
            + bf2f((uint16_t)(d.y >> 16))     * hnS[lane*4 + 3];
    #pragma unroll
    for (int off = 32; off >= 1; off >>= 1) s += __shfl_xor(s, off);
    if (lane == 0) attnS[t] = s * 0.0625f;     // 1/sqrt(256)
  }
  __syncthreads();
  float acc = 0.f;
  #pragma unroll 4
  for (int t = 0; t < 512; ++t)
    acc += attnS[t] * bf2f(y[((size_t)b*512 + t)*256 + tid]);
  if (isb) ((uint16_t*)outv)[7936 + b*256 + tid] = f2bf(acc);
  else     ((float*)outv)[7936 + b*256 + tid] = acc;
  if (tid < 31) {
    float a2 = bf2f(linb[tid]);
    for (int k = 0; k < 256; ++k) a2 += hnS[k] * bf2f(linw[tid*256 + k]);
    if (isb) ((uint16_t*)outv)[b*31 + tid] = f2bf(a2);
    else     ((float*)outv)[b*31 + tid] = a2;
  }
}

// ---------------------------------------------------------------------------
extern "C" void kernel_launch(void* const* d_in, const int* in_sizes, int n_in,
                              void* d_out, int out_size, void* d_ws, size_t ws_size,
                              hipStream_t stream)
{
  (void)in_sizes; (void)out_size;
  if (n_in < 15) return;
  const int* x   = (const int*)d_in[0];
  const int* len = (const int*)d_in[1];

  uint8_t* p = (uint8_t*)d_ws;
  auto take = [&](size_t n){ uint8_t* r = p; p += (n + 255) & ~(size_t)255; return r; };
  int*      flag  = (int*)take(256);
  uint16_t* c1bC  = (uint16_t*)take(256);
  uint16_t* c2bC  = (uint16_t*)take(256);
  uint16_t* bngC  = (uint16_t*)take(512);
  uint16_t* bnbC  = (uint16_t*)take(512);
  uint16_t* bihC  = (uint16_t*)take(2048);
  uint16_t* bhhC  = (uint16_t*)take(2048);
  uint16_t* linwC = (uint16_t*)take(15872);
  uint16_t* linbC = (uint16_t*)take(64);
  uint16_t* fragC = (uint16_t*)take(327680);
  uint16_t* fragI = (uint16_t*)take(524288);
  uint2*    fragH8= (uint2*)take(262144);
  float*    bnbuf = (float*)take(4096);
  float*    wsHf  = (float*)take(262144);
  float*    wsC   = (float*)take(262144);
  float*    hnbuf = (float*)take(262144);
  uint16_t* y     = (uint16_t*)take(67108864ull);
  uint16_t* gxb   = (uint16_t*)take(67108864ull);
  if ((size_t)(p - (uint8_t*)d_ws) > ws_size) return;

  // big converted tensors live inside gxb (dead before k_gx first writes it)
  uint16_t* etabC = gxb;
  uint16_t* c1wC  = (uint16_t*)((uint8_t*)gxb + 16u*1024*1024);
  uint16_t* c2wC  = (uint16_t*)((uint8_t*)gxb + 17u*1024*1024);
  uint16_t* wihC  = (uint16_t*)((uint8_t*)gxb + 18u*1024*1024);
  uint16_t* whhC  = (uint16_t*)((uint8_t*)gxb + 19u*1024*1024);

  k_sniff<<<1, 256, 0, stream>>>((const uint32_t*)d_in[2], flag);

  CvtArgs A;
  int c0 = 0;
  auto put = [&](int i, const void* s, uint16_t* d, int n){
    A.a[i].s = s; A.a[i].d = d; A.a[i].n = n; A.a[i].c0 = c0;
    c0 += (n + 4095) / 4096;
  };
  put(0,  d_in[2],  etabC, 6400000);
  put(1,  d_in[3],  c1wC,  49152);
  put(2,  d_in[4],  c1bC,  128);
  put(3,  d_in[5],  c2wC,  81920);
  put(4,  d_in[6],  c2bC,  128);
  put(5,  d_in[7],  bngC,  256);
  put(6,  d_in[8],  bnbC,  256);
  put(7,  d_in[9],  wihC,  262144);
  put(8,  d_in[10], whhC,  262144);
  put(9,  d_in[11], bihC,  1024);
  put(10, d_in[12], bhhC,  1024);
  put(11, d_in[13], linwC, 7936);
  put(12, d_in[14], linbC, 31);
  k_cvt<<<c0, 256, 0, stream>>>(A, flag);

  k_prep<<<512, 256, 0, stream>>>(c1wC, c2wC, wihC, whhC, fragC, fragI, fragH8,
                                  bnbuf, wsHf, wsC);
  k_conv<<<2048, 256, 0, stream>>>(x, etabC, fragC, c1bC, c2bC, y, bnbuf);
  k_bn<<<1, 256, 0, stream>>>(bngC, bnbC, bnbuf);
  for (int c = 0; c < 4; ++c) {
    k_gx<<<dim3(512, 4), 256, 0, stream>>>(y, bnbuf, fragI, bihC, bhhC, gxb, c*128);
    k_lstm<<<16, 1024, 0, stream>>>(gxb, fragH8, len, wsHf, wsC, hnbuf,
                                    c*128, 128, (c == 3) ? 1 : 0);
  }
  k_attn<<<256, 256, 0, stream>>>(y, hnbuf, linwC, linbC, d_out, flag);
}

// Round 8
// 2008.444 us; speedup vs baseline: 2.0825x; 1.3654x over previous
//
#include <hip/hip_runtime.h>
#include <stdint.h>

// ---------------------------------------------------------------------------
// RNNClassifier pipeline for MI355X (gfx950). Dtype-agnostic input handling
// (sniffer + converter to bf16). Core pipeline (MFMA, f32 accum):
//  k_prep : conv/w_ih weights -> bf16 MFMA B-frags; w_hh -> fp8 e4m3 B-frags
//           scaled x16; zero carries.
//  k_conv : embedding gather + (conv3|conv5) as one K=640 im2col GEMM -> y
//  k_bn   : finalize BN scale/shift
//  k_gx   : gx = ReLU(BN(y)) @ w_ih^T + b_ih + b_hh, scaled x256, written as
//           8KB slabs per (t, 4-row block) [nt][c16][r] bf16
//  k_lstm : v6: 64 blocks x 4 batch rows x 512 thr (8 waves, 2/SIMD).
//           R7 counters: 16 active CUs at 92% combined issue (VALU 54% +
//           MFMA 38%) -> work-per-CU bound. Rows are independent
//           recurrences, so split 4 rows/block: MFMA per CU unchanged
//           (M=16 tile, 12 pad rows) but gate/trans VALU per CU /4.
//           w_hh resident fp8 as i64 (128 VGPR). h split-fp8 in SEPARATE
//           H/L LDS planes (kills v_perm repack). Gate phase redistributed
//           via per-wave LDS scratch so every lane computes 2 real cells.
//  k_attn : attn/attn_out/logits epilogue
//
// MFMA 16x16x32 layouts (bf16 verified m89/m120; fp8 same pattern, bytes):
//   A: lane holds A[m=lane&15][k=(lane>>4)*8+j], j=0..7
//   B: lane holds B[k=(lane>>4)*8+j][n=lane&15]
//   C/D: lane holds D[m=(lane>>4)*4+r][n=lane&15], r=0..3
// ---------------------------------------------------------------------------

typedef __bf16 bf16x8 __attribute__((ext_vector_type(8)));
typedef float  f32x4  __attribute__((ext_vector_type(4)));

__device__ __forceinline__ float bf2f(uint16_t h){
  union { uint32_t u; float f; } v; v.u = ((uint32_t)h) << 16; return v.f;
}
__device__ __forceinline__ uint16_t f2bf(float f){
  union { float f; uint32_t u; } v; v.f = f;
  return (uint16_t)((v.u + 0x7FFFu + ((v.u >> 16) & 1u)) >> 16);
}
__device__ __forceinline__ bf16x8 ld_frag(const uint16_t* p){
  union { int4 i; bf16x8 b; } u; u.i = *(const int4*)p; return u.b;
}
__device__ __forceinline__ f32x4 mfma16(bf16x8 a, bf16x8 b, f32x4 c){
  return __builtin_amdgcn_mfma_f32_16x16x32_bf16(a, b, c, 0, 0, 0);
}
__device__ __forceinline__ float sigm(float x){
  return __builtin_amdgcn_rcpf(1.f + __expf(-x));
}
__device__ __forceinline__ float tanh_(float x){
  return 2.f * __builtin_amdgcn_rcpf(1.f + __expf(-2.f * x)) - 1.f;
}

typedef long i64_t;
__device__ __forceinline__ i64_t mk64(uint32_t lo, uint32_t hi){
  union { uint2 u; i64_t l; } t; t.u = make_uint2(lo, hi); return t.l;
}
__device__ __forceinline__ f32x4 mfma8(i64_t a, i64_t b, f32x4 c){
  return __builtin_amdgcn_mfma_f32_16x16x32_fp8_fp8(a, b, c, 0, 0, 0);
}
__device__ __forceinline__ void dma16(const void* g, void* l){
  __builtin_amdgcn_global_load_lds(
      (const __attribute__((address_space(1))) uint32_t*)g,
      (__attribute__((address_space(3))) uint32_t*)l, 16, 0, 0);
}
// split-fp8 h: H = fp8(16h), L = fp8(16*(16h - dec(H)))
__device__ __forceinline__ void emit2(uint8_t* bH, uint8_t* bL, int off, float h){
  float h16 = h * 16.f;
  int p1 = __builtin_amdgcn_cvt_pk_fp8_f32(h16, h16, 0, false);
  float dec = __builtin_amdgcn_cvt_f32_fp8(p1, 0);
  float r16 = (h16 - dec) * 16.f;
  int p2 = __builtin_amdgcn_cvt_pk_fp8_f32(r16, r16, 0, false);
  bH[off] = (uint8_t)(p1 & 0xff);
  bL[off] = (uint8_t)(p2 & 0xff);
}

// ---------------------------------------------------------------------------
__global__ __launch_bounds__(256) void k_sniff(const uint32_t* __restrict__ e,
                                               int* __restrict__ flag)
{
  __shared__ int cnt;
  int tid = threadIdx.x;
  if (tid == 0) cnt = 0;
  __syncthreads();
  uint32_t u = e[tid];
  uint32_t ex = (u >> 7) & 0xFFu;
  if (ex >= 0x60u && ex <= 0x7Eu) atomicAdd(&cnt, 1);
  __syncthreads();
  if (tid == 0) flag[0] = (cnt >= 192) ? 1 : 0;
}

// ---------------------------------------------------------------------------
struct CvtDesc { const void* s; uint16_t* d; int n; int c0; };
struct CvtArgs { CvtDesc a[13]; };

__global__ __launch_bounds__(256) void k_cvt(CvtArgs A, const int* __restrict__ flag)
{
  int ch = blockIdx.x;
  int i = 0;
  #pragma unroll
  for (int k = 1; k < 13; ++k) if (ch >= A.a[k].c0) i = k;
  const void* s = A.a[i].s;
  uint16_t*   d = A.a[i].d;
  int n = A.a[i].n;
  int base = (ch - A.a[i].c0) * 4096 + threadIdx.x;
  int isb = *flag;
  #pragma unroll 4
  for (int r = 0; r < 16; ++r) {
    int idx = base + r * 256;
    if (idx < n)
      d[idx] = isb ? ((const uint16_t*)s)[idx] : f2bf(((const float*)s)[idx]);
  }
}

// ---------------------------------------------------------------------------
__global__ __launch_bounds__(256) void k_prep(
    const uint16_t* __restrict__ c1w, const uint16_t* __restrict__ c2w,
    const uint16_t* __restrict__ wih, const uint16_t* __restrict__ whh,
    uint16_t* __restrict__ fragC, uint16_t* __restrict__ fragI,
    uint2* __restrict__ fragH8, float* __restrict__ bnbuf,
    float* __restrict__ wsHf, float* __restrict__ wsC)
{
  int g = blockIdx.x * 256 + threadIdx.x;
  if (g < 20480) {                       // conv B fragments (320 tiles)
    int tile = g >> 6, lane = g & 63;
    int kt = tile >> 4, nt = tile & 15;
    int q = lane >> 4, c16 = lane & 15;
    int dlt = kt >> 2;
    int o = nt * 16 + c16;
    union { int4 i; uint16_t u[8]; } v;
    #pragma unroll
    for (int j = 0; j < 8; ++j) {
      int i = (kt & 3) * 32 + q * 8 + j;
      uint16_t val = 0;
      if (o < 128) { int k = dlt - 1; if (k >= 0 && k < 3) val = c1w[(o*128 + i)*3 + k]; }
      else         { int k = dlt;     if (k < 5)           val = c2w[((o-128)*128 + i)*5 + k]; }
      v.u[j] = val;
    }
    *(int4*)(fragC + tile * 512 + lane * 8) = v.i;
  } else if (g < 53248) {                // w_ih bf16 fragments (512 tiles)
    int gg = g - 20480;
    int tile = gg >> 6, lane = gg & 63;
    int nt = tile >> 3, kt = tile & 7;
    int q = lane >> 4, c16 = lane & 15;
    *(int4*)(fragI + tile * 512 + lane * 8) =
        *(const int4*)(wih + (nt*16 + c16)*256 + kt*32 + q*8);
  } else if (g < 86016) {                // w_hh fp8 fragments (x16 scale)
    int gg = g - 53248;
    int tile = gg >> 6, lane = gg & 63;
    int nt = tile >> 3, kt = tile & 7;
    int q = lane >> 4, c16 = lane & 15;
    const uint16_t* src = whh + (nt*16 + c16)*256 + kt*32 + q*8;
    float f[8];
    #pragma unroll
    for (int j = 0; j < 8; ++j) f[j] = bf2f(src[j]) * 16.f;
    int lo = __builtin_amdgcn_cvt_pk_fp8_f32(f[0], f[1], 0, false);
    lo     = __builtin_amdgcn_cvt_pk_fp8_f32(f[2], f[3], lo, true);
    int hi = __builtin_amdgcn_cvt_pk_fp8_f32(f[4], f[5], 0, false);
    hi     = __builtin_amdgcn_cvt_pk_fp8_f32(f[6], f[7], hi, true);
    fragH8[tile*64 + lane] = make_uint2((uint32_t)lo, (uint32_t)hi);
  } else if (g < 102400) {               // zero wsHf (65536 f32)
    ((int4*)wsHf)[g - 86016] = make_int4(0,0,0,0);
  } else if (g < 118784) {               // zero wsC (65536 f32)
    ((int4*)wsC)[g - 102400] = make_int4(0,0,0,0);
  } else if (g < 118912) {               // zero bn sums (512 f32)
    ((int4*)bnbuf)[g - 118784] = make_int4(0,0,0,0);
  }
}

// ---------------------------------------------------------------------------
__global__ __launch_bounds__(256) void k_conv(
    const int* __restrict__ x, const uint16_t* __restrict__ etab,
    const uint16_t* __restrict__ fragC,
    const uint16_t* __restrict__ c1b, const uint16_t* __restrict__ c2b,
    uint16_t* __restrict__ y, float* __restrict__ bnbuf)
{
  __shared__ __align__(16) uint16_t embS[68 * 136];
  int blk = blockIdx.x;
  int b = blk >> 3, t0 = (blk & 7) * 64;
  int tid = threadIdx.x;
  int lane = tid & 63, w = tid >> 6;
  int q = lane >> 4, c16 = lane & 15;

  for (int s = tid; s < 1088; s += 256) {      // 68 rows x 16 segs of 16B
    int r = s >> 4, seg = s & 15;
    int t = t0 - 2 + r;
    int4 val = make_int4(0,0,0,0);
    if (t >= 0 && t < 512) {
      int idx = x[b*512 + t];
      val = *(const int4*)(etab + (size_t)idx*128 + seg*8);
    }
    *(int4*)(embS + r*136 + seg*8) = val;
  }
  __syncthreads();

  f32x4 acc[4][4];
  #pragma unroll
  for (int i = 0; i < 4; ++i)
    #pragma unroll
    for (int j = 0; j < 4; ++j) acc[i][j] = (f32x4){0.f,0.f,0.f,0.f};

  #pragma unroll 4
  for (int kt = 0; kt < 20; ++kt) {
    int dlt = kt >> 2;
    int i0 = (kt & 3)*32 + q*8;
    bf16x8 a[4];
    #pragma unroll
    for (int Mt = 0; Mt < 4; ++Mt)
      a[Mt] = ld_frag(embS + (Mt*16 + c16 + dlt)*136 + i0);
    #pragma unroll
    for (int ntl = 0; ntl < 4; ++ntl) {
      int nt = w*4 + ntl;
      bf16x8 bf = ld_frag(fragC + (kt*16 + nt)*512 + lane*8);
      #pragma unroll
      for (int Mt = 0; Mt < 4; ++Mt)
        acc[ntl][Mt] = mfma16(a[Mt], bf, acc[ntl][Mt]);
    }
  }

  #pragma unroll
  for (int ntl = 0; ntl < 4; ++ntl) {
    int ch = (w*4 + ntl)*16 + c16;
    float bias = bf2f(ch < 128 ? c1b[ch] : c2b[ch - 128]);
    float s0 = 0.f, s1 = 0.f;
    #pragma unroll
    for (int Mt = 0; Mt < 4; ++Mt) {
      #pragma unroll
      for (int r = 0; r < 4; ++r) {
        float v = acc[ntl][Mt][r] + bias;
        int t = t0 + Mt*16 + q*4 + r;
        y[((size_t)b*512 + t)*256 + ch] = f2bf(v);
        s0 += v; s1 += v*v;
      }
    }
    s0 += __shfl_xor(s0, 16); s0 += __shfl_xor(s0, 32);
    s1 += __shfl_xor(s1, 16); s1 += __shfl_xor(s1, 32);
    if (q == 0) { atomicAdd(&bnbuf[ch], s0); atomicAdd(&bnbuf[256 + ch], s1); }
  }
}

// ---------------------------------------------------------------------------
__global__ void k_bn(const uint16_t* __restrict__ gamma,
                     const uint16_t* __restrict__ beta,
                     float* __restrict__ bnbuf)
{
  int c = threadIdx.x;
  const float inv = 1.f / 131072.f;
  float mean = bnbuf[c] * inv;
  float var  = fmaxf(bnbuf[256 + c] * inv - mean*mean, 0.f);
  float sc   = bf2f(gamma[c]) * rsqrtf(var + 1e-5f);
  bnbuf[512 + c] = sc;
  bnbuf[768 + c] = bf2f(beta[c]) - mean * sc;
}

// ---------------------------------------------------------------------------
// k_gx: per-(t, b4) 8KB slab [nt 0..63][c16 0..15][r 0..3] bf16, value 256*g.
// ---------------------------------------------------------------------------
__global__ __launch_bounds__(256) void k_gx(
    const uint16_t* __restrict__ y, const float* __restrict__ bnbuf,
    const uint16_t* __restrict__ fragI, const uint16_t* __restrict__ bih,
    const uint16_t* __restrict__ bhh, uint16_t* __restrict__ gx, int tbase)
{
  __shared__ __align__(16) uint16_t aS[16384];
  int Mblk = blockIdx.x, Nblk = blockIdx.y;
  int tl = Mblk >> 2;
  int b0 = (Mblk & 3) * 64;
  int t = tbase + tl;
  int tid = threadIdx.x, lane = tid & 63, w = tid >> 6;
  int q = lane >> 4, c16 = lane & 15;

  for (int s = tid; s < 2048; s += 256) {
    int row = s >> 5, seg = s & 31;
    union { int4 i; uint16_t u[8]; } vv, oo;
    vv.i = *(const int4*)(y + ((size_t)(b0 + row)*512 + t)*256 + seg*8);
    #pragma unroll
    for (int j = 0; j < 8; ++j) {
      int ch = seg*8 + j;
      float f = bf2f(vv.u[j]) * bnbuf[512 + ch] + bnbuf[768 + ch];
      oo.u[j] = f2bf(fmaxf(f, 0.f));
    }
    int Mt = row >> 4, mL = row & 15, kt2 = seg >> 2, qq = seg & 3;
    *(int4*)(aS + ((Mt*8 + kt2)*64 + qq*16 + mL)*8) = oo.i;
  }
  __syncthreads();

  f32x4 acc[4][4];
  #pragma unroll
  for (int ntl = 0; ntl < 4; ++ntl) {
    int n = (Nblk*16 + w*4 + ntl)*16 + c16;
    float bias = bf2f(bih[n]) + bf2f(bhh[n]);
    #pragma unroll
    for (int Mt = 0; Mt < 4; ++Mt) acc[ntl][Mt] = (f32x4){bias,bias,bias,bias};
  }
  #pragma unroll
  for (int kt = 0; kt < 8; ++kt) {
    bf16x8 a[4];
    #pragma unroll
    for (int Mt = 0; Mt < 4; ++Mt)
      a[Mt] = ld_frag(aS + ((Mt*8 + kt)*64 + lane)*8);
    #pragma unroll
    for (int ntl = 0; ntl < 4; ++ntl) {
      int nt = Nblk*16 + w*4 + ntl;
      bf16x8 bf = ld_frag(fragI + ((size_t)(nt*8 + kt))*512 + lane*8);
      #pragma unroll
      for (int Mt = 0; Mt < 4; ++Mt)
        acc[ntl][Mt] = mfma16(a[Mt], bf, acc[ntl][Mt]);
    }
  }
  #pragma unroll
  for (int ntl = 0; ntl < 4; ++ntl) {
    int nt = Nblk*16 + w*4 + ntl;
    #pragma unroll
    for (int Mt = 0; Mt < 4; ++Mt) {
      // D rows m=q*4+r -> b4 = (Mblk&3)*16 + Mt*4 + q, in-block row r
      int b4 = (Mblk & 3)*16 + Mt*4 + q;
      uint32_t lo = (uint32_t)f2bf(acc[ntl][Mt][0]*256.f) | ((uint32_t)f2bf(acc[ntl][Mt][1]*256.f) << 16);
      uint32_t hi = (uint32_t)f2bf(acc[ntl][Mt][2]*256.f) | ((uint32_t)f2bf(acc[ntl][Mt][3]*256.f) << 16);
      uint2 vv = {lo, hi};
      *(uint2*)(gx + ((size_t)(tl*64 + b4))*4096 + (nt*16 + c16)*4) = vv;
    }
  }
}

// ---------------------------------------------------------------------------
// k_lstm v6: 64 blocks x 512 threads (8 waves, 2/SIMD). Block b4 owns batch
// rows [4*b4, 4*b4+4). Wave w owns 8 gate tiles ntg[gp]=(gp>>1)*16+2w+(gp&1)
// (units u = 32w + p*16 + c16, p = gp&1, gate = gp>>1). breg fp8 i64 =
// 128 VGPR, fully resident. h in separate H/L fp8 planes (A-frag layout,
// rows 4..15 zeroed once). After MFMA+recombine, q==0 lanes deposit gate
// values to per-wave LDS scratch [r][p][c16][gate]; every lane reads back
// its 2 real cells (m=q, u=32w+p*16+c16) and runs gates+emit.
// ---------------------------------------------------------------------------
__global__ __launch_bounds__(512, 2) void k_lstm(
    const uint16_t* __restrict__ gx, const uint2* __restrict__ fragH8,
    const int* __restrict__ lengths, float* __restrict__ wsHf,
    float* __restrict__ wsC, float* __restrict__ hn,
    int tbase, int tcount, int last)
{
  __shared__ __align__(16) uint8_t hH[2][4096];
  __shared__ __align__(16) uint8_t hL[2][4096];
  __shared__ __align__(16) uint8_t gxS[2][8192];
  __shared__ __align__(16) float   scr[8][512];    // per-wave [r][p][c16][gate]

  int b4 = blockIdx.x;
  int tid = threadIdx.x, lane = tid & 63, w = tid >> 6;   // w = 0..7
  int q = lane >> 4, c16 = lane & 15;
  int row = b4*4 + q;

  int li    = lengths[row];
  int Tmax  = lengths[b4*4];                   // sorted descending
  int liMin = lengths[b4*4 + 3];

  int ntg[8];
  i64_t breg[8][8];                            // w_hh fp8, fully resident
  #pragma unroll
  for (int gp = 0; gp < 8; ++gp) {
    ntg[gp] = (gp >> 1)*16 + 2*w + (gp & 1);
    #pragma unroll
    for (int kt = 0; kt < 8; ++kt) {
      uint2 v = fragH8[(ntg[gp]*8 + kt)*64 + lane];
      breg[gp][kt] = mk64(v.x, v.y);
    }
  }

  int up[2], off2[2];
  #pragma unroll
  for (int p = 0; p < 2; ++p) {
    int u = 32*w + p*16 + c16;
    up[p] = u;
    off2[p] = (u >> 3)*128 + q*8 + (u & 7);    // H/L plane byte offset, m=q
  }

  float cr[2], hr[2];
  #pragma unroll
  for (int p = 0; p < 2; ++p) {
    cr[p] = wsC [row*256 + up[p]];
    hr[p] = wsHf[row*256 + up[p]];
  }

  // zero both plane buffers (covers pad rows 4..15 forever)
  ((int4*)hH)[tid] = make_int4(0,0,0,0);       // 2*4096 = 512*16 bytes
  ((int4*)hL)[tid] = make_int4(0,0,0,0);
  __syncthreads();
  #pragma unroll
  for (int p = 0; p < 2; ++p)
    emit2(&hH[0][0], &hL[0][0], off2[p], hr[p]);

  // initial gx slab
  dma16((const uint8_t*)(gx + (size_t)b4*4096) + tid*16, &gxS[0][tid*16]);
  __syncthreads();

  int cur = 0;
  int tEnd = min(tbase + tcount, Tmax);
  const float C1 = 1.f/256.f, C2 = 1.f/4096.f;

  for (int t = tbase; t < tEnd; ++t) {
    // stage next step's gx
    {
      int tn = (t + 1 < tEnd) ? (t + 1 - tbase) : (t - tbase);
      dma16((const uint8_t*)(gx + ((size_t)(tn*64 + b4))*4096) + tid*16,
            &gxS[cur ^ 1][tid*16]);
    }

    // acc1 init from 256*gx (broadcast across q); acc2 zero
    f32x4 acc1[8], acc2[8];
    #pragma unroll
    for (int gp = 0; gp < 8; ++gp) {
      uint2 gg = *(const uint2*)(&gxS[cur][(ntg[gp]*16 + c16)*8]);
      acc1[gp][0] = bf2f((uint16_t)(gg.x & 0xffffu));
      acc1[gp][1] = bf2f((uint16_t)(gg.x >> 16));
      acc1[gp][2] = bf2f((uint16_t)(gg.y & 0xffffu));
      acc1[gp][3] = bf2f((uint16_t)(gg.y >> 16));
      acc2[gp] = (f32x4){0.f,0.f,0.f,0.f};
    }

    // GEMM: H and L planes, weights in registers
    #pragma unroll
    for (int kt = 0; kt < 8; ++kt) {
      int ao = ((kt*4 + q)*16 + c16)*8;
      i64_t ahi = *(const i64_t*)(&hH[cur][ao]);
      i64_t alo = *(const i64_t*)(&hL[cur][ao]);
      #pragma unroll
      for (int gp = 0; gp < 8; ++gp) {
        acc1[gp] = mfma8(ahi, breg[gp][kt], acc1[gp]);
        acc2[gp] = mfma8(alo, breg[gp][kt], acc2[gp]);
      }
    }

    // recombine + deposit (only q==0 lanes hold real rows 0..3)
    if (q == 0) {
      #pragma unroll
      for (int gp = 0; gp < 8; ++gp) {
        int p = gp & 1, gd = gp >> 1;
        #pragma unroll
        for (int r = 0; r < 4; ++r)
          scr[w][((r*2 + p)*16 + c16)*4 + gd] = acc1[gp][r]*C1 + acc2[gp][r]*C2;
      }
    }
    __builtin_amdgcn_wave_barrier();
    asm volatile("s_waitcnt lgkmcnt(0)" ::: "memory");

    // every lane: 2 real cells (m=q, u=32w+p*16+c16)
    #pragma unroll
    for (int p = 0; p < 2; ++p) {
      f32x4 gv = *(const f32x4*)(&scr[w][((q*2 + p)*16 + c16)*4]);
      float cn = sigm(gv[1])*cr[p] + sigm(gv[0])*tanh_(gv[2]);
      float hw = sigm(gv[3])*tanh_(cn);
      if (t >= liMin) {                        // masking tail
        bool upd = (t < li);
        cn = upd ? cn : cr[p];
        hw = upd ? hw : hr[p];
      }
      cr[p] = cn; hr[p] = hw;
      emit2(&hH[cur ^ 1][0], &hL[cur ^ 1][0], off2[p], hw);
    }

    __syncthreads();
    cur ^= 1;
  }

  #pragma unroll
  for (int p = 0; p < 2; ++p) {
    wsC [row*256 + up[p]] = cr[p];
    wsHf[row*256 + up[p]] = hr[p];
  }
  if (last) {
    #pragma unroll
    for (int p = 0; p < 2; ++p)
      hn[row*256 + up[p]] = hr[p];
  }
}

// ---------------------------------------------------------------------------
__global__ __launch_bounds__(256) void k_attn(
    const uint16_t* __restrict__ y, const float* __restrict__ hn,
    const uint16_t* __restrict__ linw, const uint16_t* __restrict__ linb,
    void* __restrict__ outv, const int* __restrict__ flag)
{
  __shared__ float hnS[256];
  __shared__ float attnS[512];
  int b = blockIdx.x;
  int tid = threadIdx.x, lane = tid & 63, w = tid >> 6;
  int isb = *flag;
  hnS[tid] = hn[b*256 + tid];
  __syncthreads();
  for (int t = w; t < 512; t += 4) {
    uint2 d = *(const uint2*)(y + ((size_t)b*512 + t)*256 + lane*4);
    float s = bf2f((uint16_t)(d.x & 0xffffu)) * hnS[lane*4 + 0]
            + bf2f((uint16_t)(d.x >> 16))     * hnS[lane*4 + 1]
            + bf2f((uint16_t)(d.y & 0xffffu)) * hnS[lane*4 + 2]
            + bf2f((uint16_t)(d.y >> 16))     * hnS[lane*4 + 3];
    #pragma unroll
    for (int off = 32; off >= 1; off >>= 1) s += __shfl_xor(s, off);
    if (lane == 0) attnS[t] = s * 0.0625f;     // 1/sqrt(256)
  }
  __syncthreads();
  float acc = 0.f;
  #pragma unroll 4
  for (int t = 0; t < 512; ++t)
    acc += attnS[t] * bf2f(y[((size_t)b*512 + t)*256 + tid]);
  if (isb) ((uint16_t*)outv)[7936 + b*256 + tid] = f2bf(acc);
  else     ((float*)outv)[7936 + b*256 + tid] = acc;
  if (tid < 31) {
    float a2 = bf2f(linb[tid]);
    for (int k = 0; k < 256; ++k) a2 += hnS[k] * bf2f(linw[tid*256 + k]);
    if (isb) ((uint16_t*)outv)[b*31 + tid] = f2bf(a2);
    else     ((float*)outv)[b*31 + tid] = a2;
  }
}

// ---------------------------------------------------------------------------
extern "C" void kernel_launch(void* const* d_in, const int* in_sizes, int n_in,
                              void* d_out, int out_size, void* d_ws, size_t ws_size,
                              hipStream_t stream)
{
  (void)in_sizes; (void)out_size;
  if (n_in < 15) return;
  const int* x   = (const int*)d_in[0];
  const int* len = (const int*)d_in[1];

  uint8_t* p = (uint8_t*)d_ws;
  auto take = [&](size_t n){ uint8_t* r = p; p += (n + 255) & ~(size_t)255; return r; };
  int*      flag  = (int*)take(256);
  uint16_t* c1bC  = (uint16_t*)take(256);
  uint16_t* c2bC  = (uint16_t*)take(256);
  uint16_t* bngC  = (uint16_t*)take(512);
  uint16_t* bnbC  = (uint16_t*)take(512);
  uint16_t* bihC  = (uint16_t*)take(2048);
  uint16_t* bhhC  = (uint16_t*)take(2048);
  uint16_t* linwC = (uint16_t*)take(15872);
  uint16_t* linbC = (uint16_t*)take(64);
  uint16_t* fragC = (uint16_t*)take(327680);
  uint16_t* fragI = (uint16_t*)take(524288);
  uint2*    fragH8= (uint2*)take(262144);
  float*    bnbuf = (float*)take(4096);
  float*    wsHf  = (float*)take(262144);
  float*    wsC   = (float*)take(262144);
  float*    hnbuf = (float*)take(262144);
  uint16_t* y     = (uint16_t*)take(67108864ull);
  uint16_t* gxb   = (uint16_t*)take(67108864ull);
  if ((size_t)(p - (uint8_t*)d_ws) > ws_size) return;

  // big converted tensors live inside gxb (dead before k_gx first writes it)
  uint16_t* etabC = gxb;
  uint16_t* c1wC  = (uint16_t*)((uint8_t*)gxb + 16u*1024*1024);
  uint16_t* c2wC  = (uint16_t*)((uint8_t*)gxb + 17u*1024*1024);
  uint16_t* wihC  = (uint16_t*)((uint8_t*)gxb + 18u*1024*1024);
  uint16_t* whhC  = (uint16_t*)((uint8_t*)gxb + 19u*1024*1024);

  k_sniff<<<1, 256, 0, stream>>>((const uint32_t*)d_in[2], flag);

  CvtArgs A;
  int c0 = 0;
  auto put = [&](int i, const void* s, uint16_t* d, int n){
    A.a[i].s = s; A.a[i].d = d; A.a[i].n = n; A.a[i].c0 = c0;
    c0 += (n + 4095) / 4096;
  };
  put(0,  d_in[2],  etabC, 6400000);
  put(1,  d_in[3],  c1wC,  49152);
  put(2,  d_in[4],  c1bC,  128);
  put(3,  d_in[5],  c2wC,  81920);
  put(4,  d_in[6],  c2bC,  128);
  put(5,  d_in[7],  bngC,  256);
  put(6,  d_in[8],  bnbC,  256);
  put(7,  d_in[9],  wihC,  262144);
  put(8,  d_in[10], whhC,  262144);
  put(9,  d_in[11], bihC,  1024);
  put(10, d_in[12], bhhC,  1024);
  put(11, d_in[13], linwC, 7936);
  put(12, d_in[14], linbC, 31);
  k_cvt<<<c0, 256, 0, stream>>>(A, flag);

  k_prep<<<512, 256, 0, stream>>>(c1wC, c2wC, wihC, whhC, fragC, fragI, fragH8,
                                  bnbuf, wsHf, wsC);
  k_conv<<<2048, 256, 0, stream>>>(x, etabC, fragC, c1bC, c2bC, y, bnbuf);
  k_bn<<<1, 256, 0, stream>>>(bngC, bnbC, bnbuf);
  for (int c = 0; c < 4; ++c) {
    k_gx<<<dim3(512, 4), 256, 0, stream>>>(y, bnbuf, fragI, bihC, bhhC, gxb, c*128);
    k_lstm<<<64, 512, 0, stream>>>(gxb, fragH8, len, wsHf, wsC, hnbuf,
                                   c*128, 128, (c == 3) ? 1 : 0);
  }
  k_attn<<<256, 256, 0, stream>>>(y, hnbuf, linwC, linbC, d_out, flag);
}